// Round 1
// baseline (188.918 us; speedup 1.0000x reference)
//
#include <hip/hip_runtime.h>
#include <hip/hip_bf16.h>

typedef _Float16 f16x8 __attribute__((ext_vector_type(8)));
typedef float f32x4 __attribute__((ext_vector_type(4)));
typedef unsigned long long u64;

#define NSEQ 4096
#define DIMM 1024
#define NHEAD 16
#define HD 64
#define NQKV 3072

__device__ __forceinline__ f32x4 mfma16(f16x8 a, f16x8 b, f32x4 c) {
  return __builtin_amdgcn_mfma_f32_16x16x32_f16(a, b, c, 0, 0, 0);
}

__device__ __forceinline__ void glds16(const void* g, void* l) {
  __builtin_amdgcn_global_load_lds(
      (const __attribute__((address_space(1))) void*)g,
      (__attribute__((address_space(3))) void*)l, 16, 0, 0);
}

// ---------------- prep: fp32 -> fp16 conversions ----------------
__global__ __launch_bounds__(256) void convert_x_kernel(
    const float* __restrict__ x, _Float16* __restrict__ xh) {
  const int i = blockIdx.x * 256 + threadIdx.x;  // 524288 total
  const float4 a = ((const float4*)x)[i * 2];
  const float4 b = ((const float4*)x)[i * 2 + 1];
  f16x8 o = {(_Float16)a.x, (_Float16)a.y, (_Float16)a.z, (_Float16)a.w,
             (_Float16)b.x, (_Float16)b.y, (_Float16)b.z, (_Float16)b.w};
  ((f16x8*)xh)[i] = o;
}

// W [K][Nn] fp32 -> Wt [Nn][K] fp16
__global__ __launch_bounds__(256) void transpose_w_kernel(
    const float* __restrict__ W, _Float16* __restrict__ Wt, int K, int Nn) {
  __shared__ float tile[64][65];
  const int k0 = blockIdx.x * 64, n0 = blockIdx.y * 64;
  const int tx = threadIdx.x & 63, ty = threadIdx.x >> 6;
  for (int rr = ty; rr < 64; rr += 4)
    tile[rr][tx] = W[(size_t)(k0 + rr) * Nn + n0 + tx];
  __syncthreads();
  for (int cc = ty; cc < 64; cc += 4)
    Wt[(size_t)(n0 + cc) * K + k0 + tx] = (_Float16)tile[tx][cc];
}

// ---------------- sort coords (stable by (coord_bits, idx)) ----------------
__global__ __launch_bounds__(1024) void sort_kernel(
    const float* __restrict__ c, int* __restrict__ sorted_idx,
    float* __restrict__ csort) {
  __shared__ u64 sk[NSEQ];
  const int t = threadIdx.x;
  for (int i = t; i < NSEQ; i += 1024)
    sk[i] = (((u64)__float_as_uint(c[i])) << 32) | (unsigned)i;
  __syncthreads();
  for (int k = 2; k <= NSEQ; k <<= 1) {
    for (int j = k >> 1; j > 0; j >>= 1) {
      for (int i = t; i < NSEQ; i += 1024) {
        const int ixj = i ^ j;
        if (ixj > i) {
          const bool up = ((i & k) == 0);
          const u64 a = sk[i], b = sk[ixj];
          if ((a > b) == up) { sk[i] = b; sk[ixj] = a; }
        }
      }
      __syncthreads();
    }
  }
  for (int i = t; i < NSEQ; i += 1024) {
    sorted_idx[i] = (int)(sk[i] & 0xffffffffu);
    csort[i] = __uint_as_float((unsigned)(sk[i] >> 32));
  }
}

// ---------------- per-query exact top-64 -> 256-bit window mask ----------------
__global__ __launch_bounds__(256) void mask_kernel(
    const float* __restrict__ csort, const int* __restrict__ sorted_idx,
    unsigned* __restrict__ masks) {
  __shared__ u64 sk[256];
  __shared__ unsigned lm[8];
  const int p = blockIdx.x, t = threadIdx.x;
  const int blk = p >> 6;
  int W0 = 64 * blk - 96;
  W0 = min(max(W0, 0), NSEQ - 256);
  const float cp = csort[p];
  const float d = fabsf(csort[W0 + t] - cp);
  sk[t] = (((u64)__float_as_uint(d)) << 20) |
          (((u64)(unsigned)sorted_idx[W0 + t]) << 8) | (unsigned)t;
  if (t < 8) lm[t] = 0u;
  __syncthreads();
  for (int k = 2; k <= 256; k <<= 1) {
    for (int j = k >> 1; j > 0; j >>= 1) {
      const int ixj = t ^ j;
      if (ixj > t) {
        const bool up = ((t & k) == 0);
        const u64 a = sk[t], b = sk[ixj];
        if ((a > b) == up) { sk[t] = b; sk[ixj] = a; }
      }
      __syncthreads();
    }
  }
  if (t < 64) {
    const unsigned w = (unsigned)(sk[t] & 0xffu);
    atomicOr(&lm[w >> 5], 1u << (w & 31u));
  }
  __syncthreads();
  if (t < 8) masks[p * 8 + t] = lm[t];
}

// ---------------- fp16 MFMA GEMM: C = A[M][K] * Bt[N][K]^T + bias ----------------
template <int M, int NN, int K, bool OUTF16>
__global__ __launch_bounds__(256) void gemm_kernel(
    const _Float16* __restrict__ A, const _Float16* __restrict__ Bt,
    const float* __restrict__ bias, void* __restrict__ C) {
  __shared__ __align__(128) char sA[16384];
  __shared__ __align__(128) char sB[16384];
  const int tid = threadIdx.x;
  const int lane = tid & 63, wid = tid >> 6;
  const int m0 = blockIdx.x * 128, n0 = blockIdx.y * 128;
  const int wm = (wid >> 1) * 64, wn = (wid & 1) * 64;
  const int lrow16 = lane & 15, kgrp = lane >> 4;
  f32x4 acc[4][4] = {};
  for (int k0 = 0; k0 < K; k0 += 64) {
#pragma unroll
    for (int c = 0; c < 4; ++c) {
      const int o = c * 4096 + wid * 1024 + lane * 16;
      const int row = o >> 7;
      const int inrow = (o & 127) ^ ((row & 7) << 4);
      glds16((const char*)A + (size_t)(m0 + row) * (K * 2) + k0 * 2 + inrow,
             sA + c * 4096 + wid * 1024);
      glds16((const char*)Bt + (size_t)(n0 + row) * (K * 2) + k0 * 2 + inrow,
             sB + c * 4096 + wid * 1024);
    }
    __syncthreads();
#pragma unroll
    for (int kt = 0; kt < 2; ++kt) {
      const int kb = kt * 64 + kgrp * 16;
      f16x8 af[4], bf[4];
#pragma unroll
      for (int tt = 0; tt < 4; ++tt) {
        const int ra = wm + tt * 16 + lrow16;
        af[tt] = *(const f16x8*)(sA + ra * 128 + (kb ^ ((ra & 7) << 4)));
        const int rb = wn + tt * 16 + lrow16;
        bf[tt] = *(const f16x8*)(sB + rb * 128 + (kb ^ ((rb & 7) << 4)));
      }
#pragma unroll
      for (int mt = 0; mt < 4; ++mt)
#pragma unroll
        for (int nt = 0; nt < 4; ++nt)
          acc[mt][nt] = mfma16(af[mt], bf[nt], acc[mt][nt]);
    }
    __syncthreads();
  }
#pragma unroll
  for (int nt = 0; nt < 4; ++nt) {
    const int col = n0 + wn + nt * 16 + lrow16;
    const float bv = bias[col];
#pragma unroll
    for (int mt = 0; mt < 4; ++mt) {
#pragma unroll
      for (int r = 0; r < 4; ++r) {
        const int row = m0 + wm + mt * 16 + kgrp * 4 + r;
        const float v = acc[mt][nt][r] + bv;
        if (OUTF16)
          ((_Float16*)C)[(size_t)row * NN + col] = (_Float16)v;
        else
          ((float*)C)[(size_t)row * NN + col] = v;
      }
    }
  }
}

// ---------------- permute qkv into sorted-head layouts ----------------
// Qs[h][p][d], Ks[h][p][d], Vts[h][d][p]
__global__ __launch_bounds__(256) void permute_kernel(
    const _Float16* __restrict__ qkvh, const int* __restrict__ sorted_idx,
    _Float16* __restrict__ Qs, _Float16* __restrict__ Ks,
    _Float16* __restrict__ Vts) {
  __shared__ _Float16 vt[64][66];
  const int h = blockIdx.x & 15;
  const int P0 = (blockIdx.x >> 4) * 64;
  const int tid = threadIdx.x;
#pragma unroll
  for (int it = 0; it < 2; ++it) {
    const int i = it * 256 + tid;
    const int row = i >> 3, seg = i & 7;
    const int p = P0 + row;
    const int orig = sorted_idx[p];
    const _Float16* base = qkvh + (size_t)orig * NQKV + h * 64 + seg * 8;
    f16x8 q8 = *(const f16x8*)base;
    f16x8 k8 = *(const f16x8*)(base + 1024);
    f16x8 v8 = *(const f16x8*)(base + 2048);
    *(f16x8*)(Qs + ((size_t)h * NSEQ + p) * 64 + seg * 8) = q8;
    *(f16x8*)(Ks + ((size_t)h * NSEQ + p) * 64 + seg * 8) = k8;
#pragma unroll
    for (int e = 0; e < 8; ++e) vt[row][seg * 8 + e] = v8[e];
  }
  __syncthreads();
#pragma unroll
  for (int it = 0; it < 2; ++it) {
    const int i = it * 256 + tid;
    const int d = i >> 3, seg = i & 7;
    f16x8 o;
#pragma unroll
    for (int e = 0; e < 8; ++e) o[e] = vt[seg * 8 + e][d];
    *(f16x8*)(Vts + ((size_t)h * 64 + d) * NSEQ + P0 + seg * 8) = o;
  }
}

// ---------------- fused windowed attention ----------------
__global__ __launch_bounds__(256) void attn_kernel(
    const _Float16* __restrict__ Qs, const _Float16* __restrict__ Ks,
    const _Float16* __restrict__ Vts, const unsigned* __restrict__ masks,
    const int* __restrict__ sorted_idx, _Float16* __restrict__ attn_h) {
  __shared__ __align__(128) char sK[32768];  // K window [256][64] f16 (swizzled); later P [64][256]
  __shared__ __align__(128) char sV[32768];  // Vt window [64][256] f16 (swizzled)
  const int b = blockIdx.x, h = blockIdx.y;
  const int tid = threadIdx.x, lane = tid & 63, wid = tid >> 6;
  const int W0 = min(max(64 * b - 96, 0), NSEQ - 256);
  const int lrow16 = lane & 15, kgrp = lane >> 4;
  // stage K and Vt windows (swizzled global source, linear LDS dest)
#pragma unroll
  for (int c = 0; c < 8; ++c) {
    const int o = c * 4096 + wid * 1024 + lane * 16;
    {
      const int row = o >> 7;
      const int inrow = (o & 127) ^ ((row & 7) << 4);
      glds16((const char*)Ks + (size_t)(h * NSEQ + W0 + row) * 128 + inrow,
             sK + c * 4096 + wid * 1024);
    }
    {
      const int d = o >> 9;
      const int inrow = (o & 511) ^ ((d & 7) << 4);
      glds16((const char*)Vts + (size_t)(h * 64 + d) * (NSEQ * 2) + W0 * 2 + inrow,
             sV + c * 4096 + wid * 1024);
    }
  }
  // Q fragments from global (hidden under staging)
  const int p_base = b * 64 + wid * 16;
  f16x8 aq0, aq1;
  {
    const _Float16* qp = Qs + ((size_t)h * NSEQ + p_base + lrow16) * 64 + kgrp * 8;
    aq0 = *(const f16x8*)qp;
    aq1 = *(const f16x8*)(qp + 32);
  }
  // per-lane mask bits: bit n = selected(query row kgrp*4+r, key n*16+lrow16)
  unsigned mb[4];
#pragma unroll
  for (int r = 0; r < 4; ++r) {
    const int p = p_base + kgrp * 4 + r;
    unsigned bits = 0;
#pragma unroll
    for (int n = 0; n < 16; ++n) {
      const int widx = n * 16 + lrow16;
      bits |= ((masks[p * 8 + (widx >> 5)] >> (widx & 31)) & 1u) << n;
    }
    mb[r] = bits;
  }
  __syncthreads();
  // S = Q K^T (64 queries x 256 keys per block; this wave: 16 queries)
  float sv[16][4];
#pragma unroll
  for (int n = 0; n < 16; ++n) {
    const int j = n * 16 + lrow16;
    const int sw = (j & 7) << 4;
    const char* kr = sK + j * 128;
    const f16x8 b0 = *(const f16x8*)(kr + ((kgrp * 16) ^ sw));
    const f16x8 b1 = *(const f16x8*)(kr + ((64 + kgrp * 16) ^ sw));
    f32x4 a = {};
    a = mfma16(aq0, b0, a);
    a = mfma16(aq1, b1, a);
#pragma unroll
    for (int r = 0; r < 4; ++r)
      sv[n][r] = ((mb[r] >> n) & 1u) ? a[r] * 0.125f : -1e30f;
  }
  // wave-parallel softmax across 16 lanes x 16 in-lane cols
#pragma unroll
  for (int r = 0; r < 4; ++r) {
    float m = sv[0][r];
#pragma unroll
    for (int n = 1; n < 16; ++n) m = fmaxf(m, sv[n][r]);
    m = fmaxf(m, __shfl_xor(m, 1));
    m = fmaxf(m, __shfl_xor(m, 2));
    m = fmaxf(m, __shfl_xor(m, 4));
    m = fmaxf(m, __shfl_xor(m, 8));
    float s = 0.f;
#pragma unroll
    for (int n = 0; n < 16; ++n) {
      const float e = __expf(sv[n][r] - m);
      sv[n][r] = e;
      s += e;
    }
    s += __shfl_xor(s, 1);
    s += __shfl_xor(s, 2);
    s += __shfl_xor(s, 4);
    s += __shfl_xor(s, 8);
    const float rinv = 1.f / s;
#pragma unroll
    for (int n = 0; n < 16; ++n) sv[n][r] *= rinv;
  }
  __syncthreads();  // all waves done reading K
  // write P (fp16) into sK region: [64 qrows][256 keys], swizzled
#pragma unroll
  for (int n = 0; n < 16; ++n) {
#pragma unroll
    for (int r = 0; r < 4; ++r) {
      const int lr = wid * 16 + kgrp * 4 + r;
      const int cb = (n * 16 + lrow16) * 2;
      *(_Float16*)(sK + lr * 512 + (cb ^ ((lr & 7) << 4))) = (_Float16)sv[n][r];
    }
  }
  __syncthreads();
  // O = P V  (16 queries x 64 dims per wave)
  f32x4 oacc[4] = {};
  const int arow = wid * 16 + lrow16;
  const int swa = (arow & 7) << 4;
#pragma unroll
  for (int kt = 0; kt < 8; ++kt) {
    const int kb = kt * 64 + kgrp * 16;
    const f16x8 pa = *(const f16x8*)(sK + arow * 512 + (kb ^ swa));
#pragma unroll
    for (int nt = 0; nt < 4; ++nt) {
      const int d = nt * 16 + lrow16;
      const f16x8 vb = *(const f16x8*)(sV + d * 512 + (kb ^ ((d & 7) << 4)));
      oacc[nt] = mfma16(pa, vb, oacc[nt]);
    }
  }
  // scatter back to original row order, head-interleaved [orig][h*64+d]
#pragma unroll
  for (int r = 0; r < 4; ++r) {
    const int p = p_base + kgrp * 4 + r;
    const int orig = sorted_idx[p];
    _Float16* op = attn_h + (size_t)orig * DIMM + h * 64;
#pragma unroll
    for (int nt = 0; nt < 4; ++nt)
      op[nt * 16 + lrow16] = (_Float16)oacc[nt][r];
  }
}

// ---------------- launch ----------------
extern "C" void kernel_launch(void* const* d_in, const int* in_sizes, int n_in,
                              void* d_out, int out_size, void* d_ws, size_t ws_size,
                              hipStream_t stream) {
  const float* x = (const float*)d_in[0];
  const float* cc = (const float*)d_in[1];
  const float* Wqkv = (const float*)d_in[2];
  const float* bqkv = (const float*)d_in[3];
  const float* Wout = (const float*)d_in[4];
  const float* bout = (const float*)d_in[5];
  char* ws = (char*)d_ws;

  _Float16* xh = (_Float16*)(ws + 0);                 //  8 MB
  _Float16* wqkvt = (_Float16*)(ws + 8388608);        //  6 MB
  _Float16* woutt = (_Float16*)(ws + 14680064);       //  2 MB
  _Float16* qkvh = (_Float16*)(ws + 16777216);        // 24 MB
  _Float16* Qsb = (_Float16*)(ws + 41943040);         //  8 MB
  _Float16* Ksb = (_Float16*)(ws + 50331648);         //  8 MB
  _Float16* Vtsb = (_Float16*)(ws + 58720256);        //  8 MB
  _Float16* atnh = (_Float16*)(ws + 67108864);        //  8 MB
  int* sidx = (int*)(ws + 75497472);                  // 16 KB
  float* csort = (float*)(ws + 75513856);             // 16 KB
  unsigned* msk = (unsigned*)(ws + 75530240);         // 128 KB

  convert_x_kernel<<<2048, 256, 0, stream>>>(x, xh);
  transpose_w_kernel<<<dim3(16, 48), 256, 0, stream>>>(Wqkv, wqkvt, 1024, 3072);
  transpose_w_kernel<<<dim3(16, 16), 256, 0, stream>>>(Wout, woutt, 1024, 1024);
  sort_kernel<<<1, 1024, 0, stream>>>(cc, sidx, csort);
  mask_kernel<<<4096, 256, 0, stream>>>(csort, sidx, msk);
  gemm_kernel<4096, 3072, 1024, true>
      <<<dim3(32, 24), 256, 0, stream>>>(xh, wqkvt, bqkv, qkvh);
  permute_kernel<<<1024, 256, 0, stream>>>(qkvh, sidx, Qsb, Ksb, Vtsb);
  attn_kernel<<<dim3(64, 16), 256, 0, stream>>>(Qsb, Ksb, Vtsb, msk, sidx, atnh);
  gemm_kernel<4096, 1024, 1024, false>
      <<<dim3(32, 8), 256, 0, stream>>>(atnh, woutt, bout, d_out);
}

// Round 2
// 149.870 us; speedup vs baseline: 1.2605x; 1.2605x over previous
//
#include <hip/hip_runtime.h>
#include <hip/hip_bf16.h>

typedef _Float16 f16x8 __attribute__((ext_vector_type(8)));
typedef float f32x4 __attribute__((ext_vector_type(4)));
typedef unsigned long long u64;

#define NSEQ 4096
#define DIMM 1024
#define NHEAD 16
#define HD 64
#define NQKV 3072

__device__ __forceinline__ f32x4 mfma16(f16x8 a, f16x8 b, f32x4 c) {
  return __builtin_amdgcn_mfma_f32_16x16x32_f16(a, b, c, 0, 0, 0);
}

__device__ __forceinline__ void glds16(const void* g, void* l) {
  __builtin_amdgcn_global_load_lds(
      (const __attribute__((address_space(1))) void*)g,
      (__attribute__((address_space(3))) void*)l, 16, 0, 0);
}

// ---------------- prep: fp32 -> fp16 conversions ----------------
__global__ __launch_bounds__(256) void convert_x_kernel(
    const float* __restrict__ x, _Float16* __restrict__ xh) {
  const int i = blockIdx.x * 256 + threadIdx.x;  // 524288 total
  const float4 a = ((const float4*)x)[i * 2];
  const float4 b = ((const float4*)x)[i * 2 + 1];
  f16x8 o = {(_Float16)a.x, (_Float16)a.y, (_Float16)a.z, (_Float16)a.w,
             (_Float16)b.x, (_Float16)b.y, (_Float16)b.z, (_Float16)b.w};
  ((f16x8*)xh)[i] = o;
}

// W [K][Nn] fp32 -> Wt [Nn][K] fp16
__global__ __launch_bounds__(256) void transpose_w_kernel(
    const float* __restrict__ W, _Float16* __restrict__ Wt, int K, int Nn) {
  __shared__ float tile[64][65];
  const int k0 = blockIdx.x * 64, n0 = blockIdx.y * 64;
  const int tx = threadIdx.x & 63, ty = threadIdx.x >> 6;
  for (int rr = ty; rr < 64; rr += 4)
    tile[rr][tx] = W[(size_t)(k0 + rr) * Nn + n0 + tx];
  __syncthreads();
  for (int cc = ty; cc < 64; cc += 4)
    Wt[(size_t)(n0 + cc) * K + k0 + tx] = (_Float16)tile[tx][cc];
}

// ---------------- rank sort: exact stable sort by (coord_bits, idx) ----------------
// rank_i = #{ j : (bits_j, j) < (bits_i, i) } ; unique keys -> direct scatter.
__global__ __launch_bounds__(256) void rank_sort_kernel(
    const float* __restrict__ c, int* __restrict__ sorted_idx,
    float* __restrict__ csort) {
  __shared__ float sc[NSEQ];
  const int t = threadIdx.x;
#pragma unroll
  for (int it = 0; it < 4; ++it) {
    const int i = it * 256 + t;
    ((float4*)sc)[i] = ((const float4*)c)[i];
  }
  __syncthreads();
  const int elem = blockIdx.x * 32 + (t >> 3);
  const int s = t & 7;
  const unsigned mybits = __float_as_uint(sc[elem]);
  int cnt = 0;
#pragma unroll 8
  for (int m = 0; m < 512; ++m) {
    const int j = s + (m << 3);
    const unsigned bj = __float_as_uint(sc[j]);
    cnt += (bj < mybits || (bj == mybits && j < elem)) ? 1 : 0;
  }
  cnt += __shfl_xor(cnt, 1);
  cnt += __shfl_xor(cnt, 2);
  cnt += __shfl_xor(cnt, 4);
  if (s == 0) {
    sorted_idx[cnt] = elem;
    csort[cnt] = sc[elem];
  }
}

// ---------------- per-query exact top-64 -> 256-bit window mask ----------------
__global__ __launch_bounds__(256) void mask_kernel(
    const float* __restrict__ csort, const int* __restrict__ sorted_idx,
    unsigned* __restrict__ masks) {
  __shared__ u64 sk[256];
  __shared__ unsigned lm[8];
  const int p = blockIdx.x, t = threadIdx.x;
  const int blk = p >> 6;
  int W0 = 64 * blk - 96;
  W0 = min(max(W0, 0), NSEQ - 256);
  const float cp = csort[p];
  const float d = fabsf(csort[W0 + t] - cp);
  sk[t] = (((u64)__float_as_uint(d)) << 20) |
          (((u64)(unsigned)sorted_idx[W0 + t]) << 8) | (unsigned)t;
  if (t < 8) lm[t] = 0u;
  __syncthreads();
  for (int k = 2; k <= 256; k <<= 1) {
    for (int j = k >> 1; j > 0; j >>= 1) {
      const int ixj = t ^ j;
      if (ixj > t) {
        const bool up = ((t & k) == 0);
        const u64 a = sk[t], b = sk[ixj];
        if ((a > b) == up) { sk[t] = b; sk[ixj] = a; }
      }
      __syncthreads();
    }
  }
  if (t < 64) {
    const unsigned w = (unsigned)(sk[t] & 0xffu);
    atomicOr(&lm[w >> 5], 1u << (w & 31u));
  }
  __syncthreads();
  if (t < 8) masks[p * 8 + t] = lm[t];
}

// ---------------- fp16 MFMA GEMM: C = A[M][K] * Bt[N][K]^T + bias ----------------
template <int M, int NN, int K, bool OUTF16>
__global__ __launch_bounds__(256) void gemm_kernel(
    const _Float16* __restrict__ A, const _Float16* __restrict__ Bt,
    const float* __restrict__ bias, void* __restrict__ C) {
  __shared__ __align__(128) char sA[16384];
  __shared__ __align__(128) char sB[16384];
  const int tid = threadIdx.x;
  const int lane = tid & 63, wid = tid >> 6;
  const int m0 = blockIdx.x * 128, n0 = blockIdx.y * 128;
  const int wm = (wid >> 1) * 64, wn = (wid & 1) * 64;
  const int lrow16 = lane & 15, kgrp = lane >> 4;
  f32x4 acc[4][4] = {};
  for (int k0 = 0; k0 < K; k0 += 64) {
#pragma unroll
    for (int c = 0; c < 4; ++c) {
      const int o = c * 4096 + wid * 1024 + lane * 16;
      const int row = o >> 7;
      const int inrow = (o & 127) ^ ((row & 7) << 4);
      glds16((const char*)A + (size_t)(m0 + row) * (K * 2) + k0 * 2 + inrow,
             sA + c * 4096 + wid * 1024);
      glds16((const char*)Bt + (size_t)(n0 + row) * (K * 2) + k0 * 2 + inrow,
             sB + c * 4096 + wid * 1024);
    }
    __syncthreads();
#pragma unroll
    for (int kt = 0; kt < 2; ++kt) {
      const int kb = kt * 64 + kgrp * 16;
      f16x8 af[4], bf[4];
#pragma unroll
      for (int tt = 0; tt < 4; ++tt) {
        const int ra = wm + tt * 16 + lrow16;
        af[tt] = *(const f16x8*)(sA + ra * 128 + (kb ^ ((ra & 7) << 4)));
        const int rb = wn + tt * 16 + lrow16;
        bf[tt] = *(const f16x8*)(sB + rb * 128 + (kb ^ ((rb & 7) << 4)));
      }
#pragma unroll
      for (int mt = 0; mt < 4; ++mt)
#pragma unroll
        for (int nt = 0; nt < 4; ++nt)
          acc[mt][nt] = mfma16(af[mt], bf[nt], acc[mt][nt]);
    }
    __syncthreads();
  }
#pragma unroll
  for (int nt = 0; nt < 4; ++nt) {
    const int col = n0 + wn + nt * 16 + lrow16;
    const float bv = bias[col];
#pragma unroll
    for (int mt = 0; mt < 4; ++mt) {
#pragma unroll
      for (int r = 0; r < 4; ++r) {
        const int row = m0 + wm + mt * 16 + kgrp * 4 + r;
        const float v = acc[mt][nt][r] + bv;
        if (OUTF16)
          ((_Float16*)C)[(size_t)row * NN + col] = (_Float16)v;
        else
          ((float*)C)[(size_t)row * NN + col] = v;
      }
    }
  }
}

// ---------------- permute qkv into sorted-head layouts ----------------
// Qs[h][p][d], Ks[h][p][d], Vts[h][d][p]
__global__ __launch_bounds__(256) void permute_kernel(
    const _Float16* __restrict__ qkvh, const int* __restrict__ sorted_idx,
    _Float16* __restrict__ Qs, _Float16* __restrict__ Ks,
    _Float16* __restrict__ Vts) {
  __shared__ _Float16 vt[64][66];
  const int h = blockIdx.x & 15;
  const int P0 = (blockIdx.x >> 4) * 64;
  const int tid = threadIdx.x;
#pragma unroll
  for (int it = 0; it < 2; ++it) {
    const int i = it * 256 + tid;
    const int row = i >> 3, seg = i & 7;
    const int p = P0 + row;
    const int orig = sorted_idx[p];
    const _Float16* base = qkvh + (size_t)orig * NQKV + h * 64 + seg * 8;
    f16x8 q8 = *(const f16x8*)base;
    f16x8 k8 = *(const f16x8*)(base + 1024);
    f16x8 v8 = *(const f16x8*)(base + 2048);
    *(f16x8*)(Qs + ((size_t)h * NSEQ + p) * 64 + seg * 8) = q8;
    *(f16x8*)(Ks + ((size_t)h * NSEQ + p) * 64 + seg * 8) = k8;
#pragma unroll
    for (int e = 0; e < 8; ++e) vt[row][seg * 8 + e] = v8[e];
  }
  __syncthreads();
#pragma unroll
  for (int it = 0; it < 2; ++it) {
    const int i = it * 256 + tid;
    const int d = i >> 3, seg = i & 7;
    f16x8 o;
#pragma unroll
    for (int e = 0; e < 8; ++e) o[e] = vt[seg * 8 + e][d];
    *(f16x8*)(Vts + ((size_t)h * 64 + d) * NSEQ + P0 + seg * 8) = o;
  }
}

// ---------------- fused windowed attention ----------------
__global__ __launch_bounds__(256) void attn_kernel(
    const _Float16* __restrict__ Qs, const _Float16* __restrict__ Ks,
    const _Float16* __restrict__ Vts, const unsigned* __restrict__ masks,
    const int* __restrict__ sorted_idx, _Float16* __restrict__ attn_h) {
  __shared__ __align__(128) char sK[32768];  // K window [256][64] f16 (swizzled); later P [64][256]
  __shared__ __align__(128) char sV[32768];  // Vt window [64][256] f16 (swizzled)
  const int b = blockIdx.x, h = blockIdx.y;
  const int tid = threadIdx.x, lane = tid & 63, wid = tid >> 6;
  const int W0 = min(max(64 * b - 96, 0), NSEQ - 256);
  const int lrow16 = lane & 15, kgrp = lane >> 4;
  // stage K and Vt windows (swizzled global source, linear LDS dest)
#pragma unroll
  for (int c = 0; c < 8; ++c) {
    const int o = c * 4096 + wid * 1024 + lane * 16;
    {
      const int row = o >> 7;
      const int inrow = (o & 127) ^ ((row & 7) << 4);
      glds16((const char*)Ks + (size_t)(h * NSEQ + W0 + row) * 128 + inrow,
             sK + c * 4096 + wid * 1024);
    }
    {
      const int d = o >> 9;
      const int inrow = (o & 511) ^ ((d & 7) << 4);
      glds16((const char*)Vts + (size_t)(h * 64 + d) * (NSEQ * 2) + W0 * 2 + inrow,
             sV + c * 4096 + wid * 1024);
    }
  }
  // Q fragments from global (hidden under staging)
  const int p_base = b * 64 + wid * 16;
  f16x8 aq0, aq1;
  {
    const _Float16* qp = Qs + ((size_t)h * NSEQ + p_base + lrow16) * 64 + kgrp * 8;
    aq0 = *(const f16x8*)qp;
    aq1 = *(const f16x8*)(qp + 32);
  }
  // per-lane mask bits: bit n = selected(query row kgrp*4+r, key n*16+lrow16)
  unsigned mb[4];
#pragma unroll
  for (int r = 0; r < 4; ++r) {
    const int p = p_base + kgrp * 4 + r;
    unsigned bits = 0;
#pragma unroll
    for (int n = 0; n < 16; ++n) {
      const int widx = n * 16 + lrow16;
      bits |= ((masks[p * 8 + (widx >> 5)] >> (widx & 31)) & 1u) << n;
    }
    mb[r] = bits;
  }
  __syncthreads();
  // S = Q K^T (64 queries x 256 keys per block; this wave: 16 queries)
  float sv[16][4];
#pragma unroll
  for (int n = 0; n < 16; ++n) {
    const int j = n * 16 + lrow16;
    const int sw = (j & 7) << 4;
    const char* kr = sK + j * 128;
    const f16x8 b0 = *(const f16x8*)(kr + ((kgrp * 16) ^ sw));
    const f16x8 b1 = *(const f16x8*)(kr + ((64 + kgrp * 16) ^ sw));
    f32x4 a = {};
    a = mfma16(aq0, b0, a);
    a = mfma16(aq1, b1, a);
#pragma unroll
    for (int r = 0; r < 4; ++r)
      sv[n][r] = ((mb[r] >> n) & 1u) ? a[r] * 0.125f : -1e30f;
  }
  // wave-parallel softmax across 16 lanes x 16 in-lane cols
#pragma unroll
  for (int r = 0; r < 4; ++r) {
    float m = sv[0][r];
#pragma unroll
    for (int n = 1; n < 16; ++n) m = fmaxf(m, sv[n][r]);
    m = fmaxf(m, __shfl_xor(m, 1));
    m = fmaxf(m, __shfl_xor(m, 2));
    m = fmaxf(m, __shfl_xor(m, 4));
    m = fmaxf(m, __shfl_xor(m, 8));
    float s = 0.f;
#pragma unroll
    for (int n = 0; n < 16; ++n) {
      const float e = __expf(sv[n][r] - m);
      sv[n][r] = e;
      s += e;
    }
    s += __shfl_xor(s, 1);
    s += __shfl_xor(s, 2);
    s += __shfl_xor(s, 4);
    s += __shfl_xor(s, 8);
    const float rinv = 1.f / s;
#pragma unroll
    for (int n = 0; n < 16; ++n) sv[n][r] *= rinv;
  }
  __syncthreads();  // all waves done reading K
  // write P (fp16) into sK region: [64 qrows][256 keys], swizzled
#pragma unroll
  for (int n = 0; n < 16; ++n) {
#pragma unroll
    for (int r = 0; r < 4; ++r) {
      const int lr = wid * 16 + kgrp * 4 + r;
      const int cb = (n * 16 + lrow16) * 2;
      *(_Float16*)(sK + lr * 512 + (cb ^ ((lr & 7) << 4))) = (_Float16)sv[n][r];
    }
  }
  __syncthreads();
  // O = P V  (16 queries x 64 dims per wave)
  f32x4 oacc[4] = {};
  const int arow = wid * 16 + lrow16;
  const int swa = (arow & 7) << 4;
#pragma unroll
  for (int kt = 0; kt < 8; ++kt) {
    const int kb = kt * 64 + kgrp * 16;
    const f16x8 pa = *(const f16x8*)(sK + arow * 512 + (kb ^ swa));
#pragma unroll
    for (int nt = 0; nt < 4; ++nt) {
      const int d = nt * 16 + lrow16;
      const f16x8 vb = *(const f16x8*)(sV + d * 512 + (kb ^ ((d & 7) << 4)));
      oacc[nt] = mfma16(pa, vb, oacc[nt]);
    }
  }
  // scatter back to original row order, head-interleaved [orig][h*64+d]
#pragma unroll
  for (int r = 0; r < 4; ++r) {
    const int p = p_base + kgrp * 4 + r;
    const int orig = sorted_idx[p];
    _Float16* op = attn_h + (size_t)orig * DIMM + h * 64;
#pragma unroll
    for (int nt = 0; nt < 4; ++nt)
      op[nt * 16 + lrow16] = (_Float16)oacc[nt][r];
  }
}

// ---------------- launch ----------------
extern "C" void kernel_launch(void* const* d_in, const int* in_sizes, int n_in,
                              void* d_out, int out_size, void* d_ws, size_t ws_size,
                              hipStream_t stream) {
  const float* x = (const float*)d_in[0];
  const float* cc = (const float*)d_in[1];
  const float* Wqkv = (const float*)d_in[2];
  const float* bqkv = (const float*)d_in[3];
  const float* Wout = (const float*)d_in[4];
  const float* bout = (const float*)d_in[5];
  char* ws = (char*)d_ws;

  _Float16* xh = (_Float16*)(ws + 0);                 //  8 MB
  _Float16* wqkvt = (_Float16*)(ws + 8388608);        //  6 MB
  _Float16* woutt = (_Float16*)(ws + 14680064);       //  2 MB
  _Float16* qkvh = (_Float16*)(ws + 16777216);        // 24 MB
  _Float16* Qsb = (_Float16*)(ws + 41943040);         //  8 MB
  _Float16* Ksb = (_Float16*)(ws + 50331648);         //  8 MB
  _Float16* Vtsb = (_Float16*)(ws + 58720256);        //  8 MB
  _Float16* atnh = (_Float16*)(ws + 67108864);        //  8 MB
  int* sidx = (int*)(ws + 75497472);                  // 16 KB
  float* csort = (float*)(ws + 75513856);             // 16 KB
  unsigned* msk = (unsigned*)(ws + 75530240);         // 128 KB

  convert_x_kernel<<<2048, 256, 0, stream>>>(x, xh);
  transpose_w_kernel<<<dim3(16, 48), 256, 0, stream>>>(Wqkv, wqkvt, 1024, 3072);
  transpose_w_kernel<<<dim3(16, 16), 256, 0, stream>>>(Wout, woutt, 1024, 1024);
  rank_sort_kernel<<<128, 256, 0, stream>>>(cc, sidx, csort);
  mask_kernel<<<4096, 256, 0, stream>>>(csort, sidx, msk);
  gemm_kernel<4096, 3072, 1024, true>
      <<<dim3(32, 24), 256, 0, stream>>>(xh, wqkvt, bqkv, qkvh);
  permute_kernel<<<1024, 256, 0, stream>>>(qkvh, sidx, Qsb, Ksb, Vtsb);
  attn_kernel<<<dim3(64, 16), 256, 0, stream>>>(Qsb, Ksb, Vtsb, msk, sidx, atnh);
  gemm_kernel<4096, 1024, 1024, false>
      <<<dim3(32, 8), 256, 0, stream>>>(atnh, woutt, bout, d_out);
}

// Round 3
// 139.328 us; speedup vs baseline: 1.3559x; 1.0757x over previous
//
#include <hip/hip_runtime.h>
#include <hip/hip_bf16.h>

typedef _Float16 f16x8 __attribute__((ext_vector_type(8)));
typedef float f32x4 __attribute__((ext_vector_type(4)));
typedef unsigned long long u64;

#define NSEQ 4096
#define DIMM 1024
#define NHEAD 16
#define HD 64
#define NQKV 3072

#define BAR() asm volatile("s_barrier" ::: "memory")

__device__ __forceinline__ f32x4 mfma16(f16x8 a, f16x8 b, f32x4 c) {
  return __builtin_amdgcn_mfma_f32_16x16x32_f16(a, b, c, 0, 0, 0);
}

__device__ __forceinline__ void glds16(const void* g, void* l) {
  __builtin_amdgcn_global_load_lds(
      (const __attribute__((address_space(1))) void*)g,
      (__attribute__((address_space(3))) void*)l, 16, 0, 0);
}

// ---------------- prep: fp32 -> fp16 conversions ----------------
__global__ __launch_bounds__(256) void convert_x_kernel(
    const float* __restrict__ x, _Float16* __restrict__ xh) {
  const int i = blockIdx.x * 256 + threadIdx.x;  // 524288 total
  const float4 a = ((const float4*)x)[i * 2];
  const float4 b = ((const float4*)x)[i * 2 + 1];
  f16x8 o = {(_Float16)a.x, (_Float16)a.y, (_Float16)a.z, (_Float16)a.w,
             (_Float16)b.x, (_Float16)b.y, (_Float16)b.z, (_Float16)b.w};
  ((f16x8*)xh)[i] = o;
}

// W [K][Nn] fp32 -> Wt [Nn][K] fp16
__global__ __launch_bounds__(256) void transpose_w_kernel(
    const float* __restrict__ W, _Float16* __restrict__ Wt, int K, int Nn) {
  __shared__ float tile[64][65];
  const int k0 = blockIdx.x * 64, n0 = blockIdx.y * 64;
  const int tx = threadIdx.x & 63, ty = threadIdx.x >> 6;
  for (int rr = ty; rr < 64; rr += 4)
    tile[rr][tx] = W[(size_t)(k0 + rr) * Nn + n0 + tx];
  __syncthreads();
  for (int cc = ty; cc < 64; cc += 4)
    Wt[(size_t)(n0 + cc) * K + k0 + tx] = (_Float16)tile[tx][cc];
}

// ---------------- rank sort: exact stable sort by (coord_bits, idx) ----------------
__global__ __launch_bounds__(256) void rank_sort_kernel(
    const float* __restrict__ c, int* __restrict__ sorted_idx,
    float* __restrict__ csort) {
  __shared__ float sc[NSEQ];
  const int t = threadIdx.x;
#pragma unroll
  for (int it = 0; it < 4; ++it) {
    const int i = it * 256 + t;
    ((float4*)sc)[i] = ((const float4*)c)[i];
  }
  __syncthreads();
  const int elem = blockIdx.x * 32 + (t >> 3);
  const int s = t & 7;
  const unsigned mybits = __float_as_uint(sc[elem]);
  int cnt = 0;
#pragma unroll 8
  for (int m = 0; m < 512; ++m) {
    const int j = s + (m << 3);
    const unsigned bj = __float_as_uint(sc[j]);
    cnt += (bj < mybits || (bj == mybits && j < elem)) ? 1 : 0;
  }
  cnt += __shfl_xor(cnt, 1);
  cnt += __shfl_xor(cnt, 2);
  cnt += __shfl_xor(cnt, 4);
  if (s == 0) {
    sorted_idx[cnt] = elem;
    csort[cnt] = sc[elem];
  }
}

// ---------------- per-query exact top-64 -> 256-bit window mask ----------------
__global__ __launch_bounds__(256) void mask_kernel(
    const float* __restrict__ csort, const int* __restrict__ sorted_idx,
    unsigned* __restrict__ masks) {
  __shared__ u64 sk[256];
  __shared__ unsigned lm[8];
  const int p = blockIdx.x, t = threadIdx.x;
  const int blk = p >> 6;
  int W0 = 64 * blk - 96;
  W0 = min(max(W0, 0), NSEQ - 256);
  const float cp = csort[p];
  const float d = fabsf(csort[W0 + t] - cp);
  sk[t] = (((u64)__float_as_uint(d)) << 20) |
          (((u64)(unsigned)sorted_idx[W0 + t]) << 8) | (unsigned)t;
  if (t < 8) lm[t] = 0u;
  __syncthreads();
  for (int k = 2; k <= 256; k <<= 1) {
    for (int j = k >> 1; j > 0; j >>= 1) {
      const int ixj = t ^ j;
      if (ixj > t) {
        const bool up = ((t & k) == 0);
        const u64 a = sk[t], b = sk[ixj];
        if ((a > b) == up) { sk[t] = b; sk[ixj] = a; }
      }
      __syncthreads();
    }
  }
  if (t < 64) {
    const unsigned w = (unsigned)(sk[t] & 0xffu);
    atomicOr(&lm[w >> 5], 1u << (w & 31u));
  }
  __syncthreads();
  if (t < 8) masks[p * 8 + t] = lm[t];
}

// ================= 256x256 8-phase QKV GEMM (T2+T3+T4+T5) =================
// A [4096][1024] f16, Bt [3072][1024] f16, C = A*Bt^T + bias -> [4096][3072] f16
// 512 thr = 8 waves (2M x 4N), wave tile 128x64, BK=64, LDS 128KB (4x32KB).

__device__ __forceinline__ f16x8 ldsfrag(const char* base, int r, int g) {
  return *(const f16x8*)(base + r * 128 + ((g ^ (r & 7)) << 4));
}

// stage one half-tile (128 rows x 64 cols f16 = 16KB): 2 glds16/thread.
// gbase points at the half's row 0 in global; LDS dest linear, source pre-swizzled.
__device__ __forceinline__ void stage_half(const char* gbase, size_t kb, int t,
                                           char* lds_half, int tid) {
#pragma unroll
  for (int s = 0; s < 2; ++s) {
    const int rel = tid * 16 + s * 8192;
    const int r = rel >> 7;
    const int g = (rel >> 4) & 7;
    const int gg = g ^ (r & 7);
    glds16(gbase + (size_t)r * kb + t * 128 + gg * 16, lds_half + rel);
  }
}

__device__ __forceinline__ void rd_b(const char* Bb, int wn, int lr, int kg,
                                     f16x8 (&bf)[4][2]) {
#pragma unroll
  for (int nt = 0; nt < 4; ++nt) {
    bf[nt][0] = ldsfrag(Bb, wn + nt * 16 + lr, kg);
    bf[nt][1] = ldsfrag(Bb, wn + nt * 16 + lr, 4 + kg);
  }
}

template <int Q>
__device__ __forceinline__ void rd_a(const char* Ab, int wm, int lr, int kg,
                                     f16x8 (&af)[2][2]) {
#pragma unroll
  for (int m = 0; m < 2; ++m) {
    af[m][0] = ldsfrag(Ab, wm + (2 * Q + m) * 16 + lr, kg);
    af[m][1] = ldsfrag(Ab, wm + (2 * Q + m) * 16 + lr, 4 + kg);
  }
}

template <int Q>
__device__ __forceinline__ void do_mfma(const f16x8 (&af)[2][2],
                                        const f16x8 (&bf)[4][2],
                                        f32x4 (&acc)[8][4]) {
#pragma unroll
  for (int m = 0; m < 2; ++m)
#pragma unroll
    for (int nt = 0; nt < 4; ++nt) {
      acc[2 * Q + m][nt] = mfma16(af[m][0], bf[nt][0], acc[2 * Q + m][nt]);
      acc[2 * Q + m][nt] = mfma16(af[m][1], bf[nt][1], acc[2 * Q + m][nt]);
    }
}

// One iteration = 2 K-tiles (even -> buf0 phases 0-3, odd -> buf1 phases 4-7).
// Stage slots (hazard-free, vmcnt(4) checkpoints at end of p3/p7):
//  p0: t1.Ah0->A1  p1: t1.Ah1->A1  p2: t2.Bh0->B0  p3: t2.Bh1->B0
//  p4: t2.Ah0->A0  p5: t2.Ah1->A0  p6: t3.Bh0->B1  p7: t3.Bh1->B1
template <bool LAST>
__device__ __forceinline__ void ktile_pair(const char* Ag, const char* Bg,
                                           size_t kb, char* smem, int tid,
                                           int wm, int wn, int lr, int kg,
                                           int t1, int t2, int t3,
                                           f32x4 (&acc)[8][4]) {
  char* A0 = smem;
  char* A1 = smem + 32768;
  char* B0 = smem + 65536;
  char* B1 = smem + 98304;
  f16x8 bf[4][2], af[2][2];
  // ---- even tile (buf0) ----
  rd_b(B0, wn, lr, kg, bf);
  rd_a<0>(A0, wm, lr, kg, af);
  stage_half(Ag, kb, t1, A1, tid);
  BAR();
  __builtin_amdgcn_s_setprio(1);
  do_mfma<0>(af, bf, acc);
  __builtin_amdgcn_s_setprio(0);
  BAR();
  rd_a<1>(A0, wm, lr, kg, af);
  stage_half(Ag + 128 * kb, kb, t1, A1 + 16384, tid);
  BAR();
  __builtin_amdgcn_s_setprio(1);
  do_mfma<1>(af, bf, acc);
  __builtin_amdgcn_s_setprio(0);
  BAR();
  rd_a<2>(A0, wm, lr, kg, af);
  if (!LAST) stage_half(Bg, kb, t2, B0, tid);
  BAR();
  __builtin_amdgcn_s_setprio(1);
  do_mfma<2>(af, bf, acc);
  __builtin_amdgcn_s_setprio(0);
  BAR();
  rd_a<3>(A0, wm, lr, kg, af);
  if (!LAST) stage_half(Bg + 128 * kb, kb, t2, B0 + 16384, tid);
  BAR();
  __builtin_amdgcn_s_setprio(1);
  do_mfma<3>(af, bf, acc);
  __builtin_amdgcn_s_setprio(0);
  if (LAST)
    asm volatile("s_waitcnt vmcnt(0)" ::: "memory");
  else
    asm volatile("s_waitcnt vmcnt(4)" ::: "memory");
  BAR();
  // ---- odd tile (buf1) ----
  rd_b(B1, wn, lr, kg, bf);
  rd_a<0>(A1, wm, lr, kg, af);
  if (!LAST) stage_half(Ag, kb, t2, A0, tid);
  BAR();
  __builtin_amdgcn_s_setprio(1);
  do_mfma<0>(af, bf, acc);
  __builtin_amdgcn_s_setprio(0);
  BAR();
  rd_a<1>(A1, wm, lr, kg, af);
  if (!LAST) stage_half(Ag + 128 * kb, kb, t2, A0 + 16384, tid);
  BAR();
  __builtin_amdgcn_s_setprio(1);
  do_mfma<1>(af, bf, acc);
  __builtin_amdgcn_s_setprio(0);
  BAR();
  rd_a<2>(A1, wm, lr, kg, af);
  if (!LAST) stage_half(Bg, kb, t3, B1, tid);
  BAR();
  __builtin_amdgcn_s_setprio(1);
  do_mfma<2>(af, bf, acc);
  __builtin_amdgcn_s_setprio(0);
  BAR();
  rd_a<3>(A1, wm, lr, kg, af);
  if (!LAST) stage_half(Bg + 128 * kb, kb, t3, B1 + 16384, tid);
  BAR();
  __builtin_amdgcn_s_setprio(1);
  do_mfma<3>(af, bf, acc);
  __builtin_amdgcn_s_setprio(0);
  if (!LAST) asm volatile("s_waitcnt vmcnt(4)" ::: "memory");
  BAR();
}

__global__ __launch_bounds__(512, 2) void qkv_gemm256_kernel(
    const _Float16* __restrict__ A, const _Float16* __restrict__ Bt,
    const float* __restrict__ bias, _Float16* __restrict__ C) {
  extern __shared__ char smem[];
  const int NN = 3072;
  const size_t kb = 2048;  // K*2 bytes, K=1024
  const int tid = threadIdx.x;
  const int lane = tid & 63, wid = tid >> 6;
  const int lr = lane & 15, kg = lane >> 4;
  const int wm = (wid >> 2) * 128, wn = (wid & 3) * 64;
  // XCD-aware swizzle: 192 blocks = 8 XCDs x 24; each XCD gets 2 bx-columns.
  const int bid = blockIdx.x;
  const int flat = (bid & 7) * 24 + (bid >> 3);
  const int bx = flat / 12, by = flat % 12;
  const int m0 = bx * 256, n0 = by * 256;
  const char* Ag = (const char*)A + (size_t)m0 * kb;
  const char* Bg = (const char*)Bt + (size_t)n0 * kb;
  char* A0 = smem;
  char* B0 = smem + 65536;
  char* B1 = smem + 98304;
  f32x4 acc[8][4] = {};
  // prologue: tile0 (A+B) -> buf0, tile1 B -> buf1
  stage_half(Ag, kb, 0, A0, tid);
  stage_half(Ag + 128 * kb, kb, 0, A0 + 16384, tid);
  stage_half(Bg, kb, 0, B0, tid);
  stage_half(Bg + 128 * kb, kb, 0, B0 + 16384, tid);
  stage_half(Bg, kb, 1, B1, tid);
  stage_half(Bg + 128 * kb, kb, 1, B1 + 16384, tid);
  asm volatile("s_waitcnt vmcnt(4)" ::: "memory");
  BAR();
#pragma unroll 1
  for (int i = 0; i < 7; ++i)
    ktile_pair<false>(Ag, Bg, kb, smem, tid, wm, wn, lr, kg, 2 * i + 1,
                      2 * i + 2, 2 * i + 3, acc);
  ktile_pair<true>(Ag, Bg, kb, smem, tid, wm, wn, lr, kg, 15, 16, 17, acc);
  // epilogue
#pragma unroll
  for (int nt = 0; nt < 4; ++nt) {
    const int col = n0 + wn + nt * 16 + lr;
    const float bv = bias[col];
#pragma unroll
    for (int mt = 0; mt < 8; ++mt) {
      const int row0 = m0 + wm + mt * 16 + kg * 4;
#pragma unroll
      for (int rr = 0; rr < 4; ++rr)
        C[(size_t)(row0 + rr) * NN + col] = (_Float16)(acc[mt][nt][rr] + bv);
    }
  }
}

// ---------------- fp16 MFMA GEMM (128x128): C = A * Bt^T + bias ----------------
template <int M, int NN, int K, bool OUTF16>
__global__ __launch_bounds__(256) void gemm_kernel(
    const _Float16* __restrict__ A, const _Float16* __restrict__ Bt,
    const float* __restrict__ bias, void* __restrict__ C) {
  __shared__ __align__(128) char sA[16384];
  __shared__ __align__(128) char sB[16384];
  const int tid = threadIdx.x;
  const int lane = tid & 63, wid = tid >> 6;
  const int m0 = blockIdx.x * 128, n0 = blockIdx.y * 128;
  const int wm = (wid >> 1) * 64, wn = (wid & 1) * 64;
  const int lrow16 = lane & 15, kgrp = lane >> 4;
  f32x4 acc[4][4] = {};
  for (int k0 = 0; k0 < K; k0 += 64) {
#pragma unroll
    for (int c = 0; c < 4; ++c) {
      const int o = c * 4096 + wid * 1024 + lane * 16;
      const int row = o >> 7;
      const int inrow = (o & 127) ^ ((row & 7) << 4);
      glds16((const char*)A + (size_t)(m0 + row) * (K * 2) + k0 * 2 + inrow,
             sA + c * 4096 + wid * 1024);
      glds16((const char*)Bt + (size_t)(n0 + row) * (K * 2) + k0 * 2 + inrow,
             sB + c * 4096 + wid * 1024);
    }
    __syncthreads();
#pragma unroll
    for (int kt = 0; kt < 2; ++kt) {
      const int kb = kt * 64 + kgrp * 16;
      f16x8 af[4], bf[4];
#pragma unroll
      for (int tt = 0; tt < 4; ++tt) {
        const int ra = wm + tt * 16 + lrow16;
        af[tt] = *(const f16x8*)(sA + ra * 128 + (kb ^ ((ra & 7) << 4)));
        const int rb = wn + tt * 16 + lrow16;
        bf[tt] = *(const f16x8*)(sB + rb * 128 + (kb ^ ((rb & 7) << 4)));
      }
#pragma unroll
      for (int mt = 0; mt < 4; ++mt)
#pragma unroll
        for (int nt = 0; nt < 4; ++nt)
          acc[mt][nt] = mfma16(af[mt], bf[nt], acc[mt][nt]);
    }
    __syncthreads();
  }
#pragma unroll
  for (int nt = 0; nt < 4; ++nt) {
    const int col = n0 + wn + nt * 16 + lrow16;
    const float bv = bias[col];
#pragma unroll
    for (int mt = 0; mt < 4; ++mt) {
#pragma unroll
      for (int r = 0; r < 4; ++r) {
        const int row = m0 + wm + mt * 16 + kgrp * 4 + r;
        const float v = acc[mt][nt][r] + bv;
        if (OUTF16)
          ((_Float16*)C)[(size_t)row * NN + col] = (_Float16)v;
        else
          ((float*)C)[(size_t)row * NN + col] = v;
      }
    }
  }
}

// ---------------- permute qkv into sorted-head layouts ----------------
// Qs[h][p][d], Ks[h][p][d], Vts[h][d][p]
__global__ __launch_bounds__(256) void permute_kernel(
    const _Float16* __restrict__ qkvh, const int* __restrict__ sorted_idx,
    _Float16* __restrict__ Qs, _Float16* __restrict__ Ks,
    _Float16* __restrict__ Vts) {
  __shared__ _Float16 vt[64][66];
  const int h = blockIdx.x & 15;
  const int P0 = (blockIdx.x >> 4) * 64;
  const int tid = threadIdx.x;
#pragma unroll
  for (int it = 0; it < 2; ++it) {
    const int i = it * 256 + tid;
    const int row = i >> 3, seg = i & 7;
    const int p = P0 + row;
    const int orig = sorted_idx[p];
    const _Float16* base = qkvh + (size_t)orig * NQKV + h * 64 + seg * 8;
    f16x8 q8 = *(const f16x8*)base;
    f16x8 k8 = *(const f16x8*)(base + 1024);
    f16x8 v8 = *(const f16x8*)(base + 2048);
    *(f16x8*)(Qs + ((size_t)h * NSEQ + p) * 64 + seg * 8) = q8;
    *(f16x8*)(Ks + ((size_t)h * NSEQ + p) * 64 + seg * 8) = k8;
#pragma unroll
    for (int e = 0; e < 8; ++e) vt[row][seg * 8 + e] = v8[e];
  }
  __syncthreads();
#pragma unroll
  for (int it = 0; it < 2; ++it) {
    const int i = it * 256 + tid;
    const int d = i >> 3, seg = i & 7;
    f16x8 o;
#pragma unroll
    for (int e = 0; e < 8; ++e) o[e] = vt[seg * 8 + e][d];
    *(f16x8*)(Vts + ((size_t)h * 64 + d) * NSEQ + P0 + seg * 8) = o;
  }
}

// ---------------- fused windowed attention ----------------
__global__ __launch_bounds__(256) void attn_kernel(
    const _Float16* __restrict__ Qs, const _Float16* __restrict__ Ks,
    const _Float16* __restrict__ Vts, const unsigned* __restrict__ masks,
    const int* __restrict__ sorted_idx, _Float16* __restrict__ attn_h) {
  __shared__ __align__(128) char sK[32768];  // K window [256][64] f16; later P
  __shared__ __align__(128) char sV[32768];  // Vt window [64][256] f16
  const int b = blockIdx.x, h = blockIdx.y;
  const int tid = threadIdx.x, lane = tid & 63, wid = tid >> 6;
  const int W0 = min(max(64 * b - 96, 0), NSEQ - 256);
  const int lrow16 = lane & 15, kgrp = lane >> 4;
#pragma unroll
  for (int c = 0; c < 8; ++c) {
    const int o = c * 4096 + wid * 1024 + lane * 16;
    {
      const int row = o >> 7;
      const int inrow = (o & 127) ^ ((row & 7) << 4);
      glds16((const char*)Ks + (size_t)(h * NSEQ + W0 + row) * 128 + inrow,
             sK + c * 4096 + wid * 1024);
    }
    {
      const int d = o >> 9;
      const int inrow = (o & 511) ^ ((d & 7) << 4);
      glds16((const char*)Vts + (size_t)(h * 64 + d) * (NSEQ * 2) + W0 * 2 + inrow,
             sV + c * 4096 + wid * 1024);
    }
  }
  const int p_base = b * 64 + wid * 16;
  f16x8 aq0, aq1;
  {
    const _Float16* qp = Qs + ((size_t)h * NSEQ + p_base + lrow16) * 64 + kgrp * 8;
    aq0 = *(const f16x8*)qp;
    aq1 = *(const f16x8*)(qp + 32);
  }
  unsigned mb[4];
#pragma unroll
  for (int r = 0; r < 4; ++r) {
    const int p = p_base + kgrp * 4 + r;
    unsigned bits = 0;
#pragma unroll
    for (int n = 0; n < 16; ++n) {
      const int widx = n * 16 + lrow16;
      bits |= ((masks[p * 8 + (widx >> 5)] >> (widx & 31)) & 1u) << n;
    }
    mb[r] = bits;
  }
  __syncthreads();
  float sv[16][4];
#pragma unroll
  for (int n = 0; n < 16; ++n) {
    const int j = n * 16 + lrow16;
    const int sw = (j & 7) << 4;
    const char* kr = sK + j * 128;
    const f16x8 b0 = *(const f16x8*)(kr + ((kgrp * 16) ^ sw));
    const f16x8 b1 = *(const f16x8*)(kr + ((64 + kgrp * 16) ^ sw));
    f32x4 a = {};
    a = mfma16(aq0, b0, a);
    a = mfma16(aq1, b1, a);
#pragma unroll
    for (int r = 0; r < 4; ++r)
      sv[n][r] = ((mb[r] >> n) & 1u) ? a[r] * 0.125f : -1e30f;
  }
#pragma unroll
  for (int r = 0; r < 4; ++r) {
    float m = sv[0][r];
#pragma unroll
    for (int n = 1; n < 16; ++n) m = fmaxf(m, sv[n][r]);
    m = fmaxf(m, __shfl_xor(m, 1));
    m = fmaxf(m, __shfl_xor(m, 2));
    m = fmaxf(m, __shfl_xor(m, 4));
    m = fmaxf(m, __shfl_xor(m, 8));
    float s = 0.f;
#pragma unroll
    for (int n = 0; n < 16; ++n) {
      const float e = __expf(sv[n][r] - m);
      sv[n][r] = e;
      s += e;
    }
    s += __shfl_xor(s, 1);
    s += __shfl_xor(s, 2);
    s += __shfl_xor(s, 4);
    s += __shfl_xor(s, 8);
    const float rinv = 1.f / s;
#pragma unroll
    for (int n = 0; n < 16; ++n) sv[n][r] *= rinv;
  }
  __syncthreads();
#pragma unroll
  for (int n = 0; n < 16; ++n) {
#pragma unroll
    for (int r = 0; r < 4; ++r) {
      const int lr = wid * 16 + kgrp * 4 + r;
      const int cb = (n * 16 + lrow16) * 2;
      *(_Float16*)(sK + lr * 512 + (cb ^ ((lr & 7) << 4))) = (_Float16)sv[n][r];
    }
  }
  __syncthreads();
  f32x4 oacc[4] = {};
  const int arow = wid * 16 + lrow16;
  const int swa = (arow & 7) << 4;
#pragma unroll
  for (int kt = 0; kt < 8; ++kt) {
    const int kb = kt * 64 + kgrp * 16;
    const f16x8 pa = *(const f16x8*)(sK + arow * 512 + (kb ^ swa));
#pragma unroll
    for (int nt = 0; nt < 4; ++nt) {
      const int d = nt * 16 + lrow16;
      const f16x8 vb = *(const f16x8*)(sV + d * 512 + (kb ^ ((d & 7) << 4)));
      oacc[nt] = mfma16(pa, vb, oacc[nt]);
    }
  }
#pragma unroll
  for (int r = 0; r < 4; ++r) {
    const int p = p_base + kgrp * 4 + r;
    const int orig = sorted_idx[p];
    _Float16* op = attn_h + (size_t)orig * DIMM + h * 64;
#pragma unroll
    for (int nt = 0; nt < 4; ++nt)
      op[nt * 16 + lrow16] = (_Float16)oacc[nt][r];
  }
}

// ---------------- launch ----------------
extern "C" void kernel_launch(void* const* d_in, const int* in_sizes, int n_in,
                              void* d_out, int out_size, void* d_ws, size_t ws_size,
                              hipStream_t stream) {
  const float* x = (const float*)d_in[0];
  const float* cc = (const float*)d_in[1];
  const float* Wqkv = (const float*)d_in[2];
  const float* bqkv = (const float*)d_in[3];
  const float* Wout = (const float*)d_in[4];
  const float* bout = (const float*)d_in[5];
  char* ws = (char*)d_ws;

  _Float16* xh = (_Float16*)(ws + 0);                 //  8 MB
  _Float16* wqkvt = (_Float16*)(ws + 8388608);        //  6 MB
  _Float16* woutt = (_Float16*)(ws + 14680064);       //  2 MB
  _Float16* qkvh = (_Float16*)(ws + 16777216);        // 24 MB
  _Float16* Qsb = (_Float16*)(ws + 41943040);         //  8 MB
  _Float16* Ksb = (_Float16*)(ws + 50331648);         //  8 MB
  _Float16* Vtsb = (_Float16*)(ws + 58720256);        //  8 MB
  _Float16* atnh = (_Float16*)(ws + 67108864);        //  8 MB
  int* sidx = (int*)(ws + 75497472);                  // 16 KB
  float* csort = (float*)(ws + 75513856);             // 16 KB
  unsigned* msk = (unsigned*)(ws + 75530240);         // 128 KB

  hipFuncSetAttribute((const void*)qkv_gemm256_kernel,
                      hipFuncAttributeMaxDynamicSharedMemorySize, 131072);

  convert_x_kernel<<<2048, 256, 0, stream>>>(x, xh);
  transpose_w_kernel<<<dim3(16, 48), 256, 0, stream>>>(Wqkv, wqkvt, 1024, 3072);
  transpose_w_kernel<<<dim3(16, 16), 256, 0, stream>>>(Wout, woutt, 1024, 1024);
  rank_sort_kernel<<<128, 256, 0, stream>>>(cc, sidx, csort);
  mask_kernel<<<4096, 256, 0, stream>>>(csort, sidx, msk);
  qkv_gemm256_kernel<<<192, 512, 131072, stream>>>(xh, wqkvt, bqkv, qkvh);
  permute_kernel<<<1024, 256, 0, stream>>>(qkvh, sidx, Qsb, Ksb, Vtsb);
  attn_kernel<<<dim3(64, 16), 256, 0, stream>>>(Qsb, Ksb, Vtsb, msk, sidx, atnh);
  gemm_kernel<4096, 1024, 1024, false>
      <<<dim3(32, 8), 256, 0, stream>>>(atnh, woutt, bout, d_out);
}

// Round 4
// 125.775 us; speedup vs baseline: 1.5020x; 1.1078x over previous
//
#include <hip/hip_runtime.h>
#include <hip/hip_bf16.h>

typedef _Float16 f16x8 __attribute__((ext_vector_type(8)));
typedef float f32x4 __attribute__((ext_vector_type(4)));
typedef unsigned long long u64;

#define NSEQ 4096
#define DIMM 1024
#define NHEAD 16
#define HD 64
#define NQKV 3072

#define BAR() asm volatile("s_barrier" ::: "memory")

__device__ __forceinline__ f32x4 mfma16(f16x8 a, f16x8 b, f32x4 c) {
  return __builtin_amdgcn_mfma_f32_16x16x32_f16(a, b, c, 0, 0, 0);
}

__device__ __forceinline__ void glds16(const void* g, void* l) {
  __builtin_amdgcn_global_load_lds(
      (const __attribute__((address_space(1))) void*)g,
      (__attribute__((address_space(3))) void*)l, 16, 0, 0);
}

// ---------------- prep: fp32 -> fp16 conversions ----------------
__global__ __launch_bounds__(256) void convert_x_kernel(
    const float* __restrict__ x, _Float16* __restrict__ xh) {
  const int i = blockIdx.x * 256 + threadIdx.x;  // 524288 total
  const float4 a = ((const float4*)x)[i * 2];
  const float4 b = ((const float4*)x)[i * 2 + 1];
  f16x8 o = {(_Float16)a.x, (_Float16)a.y, (_Float16)a.z, (_Float16)a.w,
             (_Float16)b.x, (_Float16)b.y, (_Float16)b.z, (_Float16)b.w};
  ((f16x8*)xh)[i] = o;
}

// W [K][Nn] fp32 -> Wt [Nn][K] fp16
__global__ __launch_bounds__(256) void transpose_w_kernel(
    const float* __restrict__ W, _Float16* __restrict__ Wt, int K, int Nn) {
  __shared__ float tile[64][65];
  const int k0 = blockIdx.x * 64, n0 = blockIdx.y * 64;
  const int tx = threadIdx.x & 63, ty = threadIdx.x >> 6;
  for (int rr = ty; rr < 64; rr += 4)
    tile[rr][tx] = W[(size_t)(k0 + rr) * Nn + n0 + tx];
  __syncthreads();
  for (int cc = ty; cc < 64; cc += 4)
    Wt[(size_t)(n0 + cc) * K + k0 + tx] = (_Float16)tile[tx][cc];
}

// ---------------- rank sort: exact stable sort by (coord_bits, idx) ----------------
__global__ __launch_bounds__(256) void rank_sort_kernel(
    const float* __restrict__ c, int* __restrict__ sorted_idx,
    float* __restrict__ csort) {
  __shared__ float sc[NSEQ];
  const int t = threadIdx.x;
#pragma unroll
  for (int it = 0; it < 4; ++it) {
    const int i = it * 256 + t;
    ((float4*)sc)[i] = ((const float4*)c)[i];
  }
  __syncthreads();
  const int elem = blockIdx.x * 32 + (t >> 3);
  const int s = t & 7;
  const unsigned mybits = __float_as_uint(sc[elem]);
  int cnt = 0;
#pragma unroll 8
  for (int m = 0; m < 512; ++m) {
    const int j = s + (m << 3);
    const unsigned bj = __float_as_uint(sc[j]);
    cnt += (bj < mybits || (bj == mybits && j < elem)) ? 1 : 0;
  }
  cnt += __shfl_xor(cnt, 1);
  cnt += __shfl_xor(cnt, 2);
  cnt += __shfl_xor(cnt, 4);
  if (s == 0) {
    sorted_idx[cnt] = elem;
    csort[cnt] = sc[elem];
  }
}

// ---------------- per-query exact top-64 -> 256-bit window mask ----------------
// Wave-per-query register bitonic sort of 256 keys (e = r*64 + lane), no barriers.
__global__ __launch_bounds__(256) void mask_kernel(
    const float* __restrict__ csort, const int* __restrict__ sorted_idx,
    unsigned* __restrict__ masks) {
  __shared__ unsigned lm[4][8];
  const int tid = threadIdx.x, lane = tid & 63, wid = tid >> 6;
  const int p = blockIdx.x * 4 + wid;  // all 4 waves share (p>>6)
  int W0 = 64 * (p >> 6) - 96;
  W0 = min(max(W0, 0), NSEQ - 256);
  const float cp = csort[p];
  u64 key[4];
#pragma unroll
  for (int r = 0; r < 4; ++r) {
    const int w = r * 64 + lane;
    const float d = fabsf(csort[W0 + w] - cp);
    key[r] = (((u64)__float_as_uint(d)) << 20) |
             (((u64)(unsigned)sorted_idx[W0 + w]) << 8) | (unsigned)w;
  }
  if (lane < 8) lm[wid][lane] = 0u;
#pragma unroll
  for (int k = 2; k <= 256; k <<= 1) {
#pragma unroll
    for (int j = k >> 1; j > 0; j >>= 1) {
      if (j >= 64) {
        const int rj = j >> 6;
#pragma unroll
        for (int r = 0; r < 4; ++r) {
          const int rp = r ^ rj;
          if (rp > r) {
            const bool up = (((r * 64) & k) == 0);
            const u64 a = key[r], b2 = key[rp];
            const bool sw = (a > b2) == up;
            key[r] = sw ? b2 : a;
            key[rp] = sw ? a : b2;
          }
        }
      } else {
#pragma unroll
        for (int r = 0; r < 4; ++r) {
          const u64 pv = __shfl_xor(key[r], j);
          const bool up = (((r * 64 + lane) & k) == 0);
          const bool lower = ((lane & j) == 0);
          const bool takemin = (lower == up);
          const u64 mn = key[r] < pv ? key[r] : pv;
          const u64 mx = key[r] < pv ? pv : key[r];
          key[r] = takemin ? mn : mx;
        }
      }
    }
  }
  // after ascending sort, ranks 0..63 live in reg 0 across the 64 lanes
  const unsigned w0 = (unsigned)(key[0] & 0xffu);
  atomicOr(&lm[wid][w0 >> 5], 1u << (w0 & 31u));
  __syncthreads();
  if (lane < 8) masks[p * 8 + lane] = lm[wid][lane];
}

// ================= shared 8-phase GEMM helpers =================
__device__ __forceinline__ f16x8 ldsfrag(const char* base, int r, int g) {
  return *(const f16x8*)(base + r * 128 + ((g ^ (r & 7)) << 4));
}

// stage one half-tile (128 rows x 64 cols f16 = 16KB): 2 glds16/thread.
__device__ __forceinline__ void stage_half(const char* gbase, size_t kb, int t,
                                           char* lds_half, int tid) {
#pragma unroll
  for (int s = 0; s < 2; ++s) {
    const int rel = tid * 16 + s * 8192;
    const int r = rel >> 7;
    const int g = (rel >> 4) & 7;
    const int gg = g ^ (r & 7);
    glds16(gbase + (size_t)r * kb + t * 128 + gg * 16, lds_half + rel);
  }
}

__device__ __forceinline__ void rd_b(const char* Bb, int wn, int lr, int kg,
                                     f16x8 (&bf)[4][2]) {
#pragma unroll
  for (int nt = 0; nt < 4; ++nt) {
    bf[nt][0] = ldsfrag(Bb, wn + nt * 16 + lr, kg);
    bf[nt][1] = ldsfrag(Bb, wn + nt * 16 + lr, 4 + kg);
  }
}

// ================= 256x256 8-phase QKV GEMM =================
template <int Q>
__device__ __forceinline__ void rd_a(const char* Ab, int wm, int lr, int kg,
                                     f16x8 (&af)[2][2]) {
#pragma unroll
  for (int m = 0; m < 2; ++m) {
    af[m][0] = ldsfrag(Ab, wm + (2 * Q + m) * 16 + lr, kg);
    af[m][1] = ldsfrag(Ab, wm + (2 * Q + m) * 16 + lr, 4 + kg);
  }
}

template <int Q>
__device__ __forceinline__ void do_mfma(const f16x8 (&af)[2][2],
                                        const f16x8 (&bf)[4][2],
                                        f32x4 (&acc)[8][4]) {
#pragma unroll
  for (int m = 0; m < 2; ++m)
#pragma unroll
    for (int nt = 0; nt < 4; ++nt) {
      acc[2 * Q + m][nt] = mfma16(af[m][0], bf[nt][0], acc[2 * Q + m][nt]);
      acc[2 * Q + m][nt] = mfma16(af[m][1], bf[nt][1], acc[2 * Q + m][nt]);
    }
}

template <bool LAST>
__device__ __forceinline__ void ktile_pair(const char* Ag, const char* Bg,
                                           size_t kb, char* smem, int tid,
                                           int wm, int wn, int lr, int kg,
                                           int t1, int t2, int t3,
                                           f32x4 (&acc)[8][4]) {
  char* A0 = smem;
  char* A1 = smem + 32768;
  char* B0 = smem + 65536;
  char* B1 = smem + 98304;
  f16x8 bf[4][2], af[2][2];
  rd_b(B0, wn, lr, kg, bf);
  rd_a<0>(A0, wm, lr, kg, af);
  stage_half(Ag, kb, t1, A1, tid);
  BAR();
  __builtin_amdgcn_s_setprio(1);
  do_mfma<0>(af, bf, acc);
  __builtin_amdgcn_s_setprio(0);
  BAR();
  rd_a<1>(A0, wm, lr, kg, af);
  stage_half(Ag + 128 * kb, kb, t1, A1 + 16384, tid);
  BAR();
  __builtin_amdgcn_s_setprio(1);
  do_mfma<1>(af, bf, acc);
  __builtin_amdgcn_s_setprio(0);
  BAR();
  rd_a<2>(A0, wm, lr, kg, af);
  if (!LAST) stage_half(Bg, kb, t2, B0, tid);
  BAR();
  __builtin_amdgcn_s_setprio(1);
  do_mfma<2>(af, bf, acc);
  __builtin_amdgcn_s_setprio(0);
  BAR();
  rd_a<3>(A0, wm, lr, kg, af);
  if (!LAST) stage_half(Bg + 128 * kb, kb, t2, B0 + 16384, tid);
  BAR();
  __builtin_amdgcn_s_setprio(1);
  do_mfma<3>(af, bf, acc);
  __builtin_amdgcn_s_setprio(0);
  if (LAST)
    asm volatile("s_waitcnt vmcnt(0)" ::: "memory");
  else
    asm volatile("s_waitcnt vmcnt(4)" ::: "memory");
  BAR();
  rd_b(B1, wn, lr, kg, bf);
  rd_a<0>(A1, wm, lr, kg, af);
  if (!LAST) stage_half(Ag, kb, t2, A0, tid);
  BAR();
  __builtin_amdgcn_s_setprio(1);
  do_mfma<0>(af, bf, acc);
  __builtin_amdgcn_s_setprio(0);
  BAR();
  rd_a<1>(A1, wm, lr, kg, af);
  if (!LAST) stage_half(Ag + 128 * kb, kb, t2, A0 + 16384, tid);
  BAR();
  __builtin_amdgcn_s_setprio(1);
  do_mfma<1>(af, bf, acc);
  __builtin_amdgcn_s_setprio(0);
  BAR();
  rd_a<2>(A1, wm, lr, kg, af);
  if (!LAST) stage_half(Bg, kb, t3, B1, tid);
  BAR();
  __builtin_amdgcn_s_setprio(1);
  do_mfma<2>(af, bf, acc);
  __builtin_amdgcn_s_setprio(0);
  BAR();
  rd_a<3>(A1, wm, lr, kg, af);
  if (!LAST) stage_half(Bg + 128 * kb, kb, t3, B1 + 16384, tid);
  BAR();
  __builtin_amdgcn_s_setprio(1);
  do_mfma<3>(af, bf, acc);
  __builtin_amdgcn_s_setprio(0);
  if (!LAST) asm volatile("s_waitcnt vmcnt(4)" ::: "memory");
  BAR();
}

__global__ __launch_bounds__(512, 2) void qkv_gemm256_kernel(
    const _Float16* __restrict__ A, const _Float16* __restrict__ Bt,
    const float* __restrict__ bias, _Float16* __restrict__ C) {
  extern __shared__ char smem[];
  const int NN = 3072;
  const size_t kb = 2048;
  const int tid = threadIdx.x;
  const int lane = tid & 63, wid = tid >> 6;
  const int lr = lane & 15, kg = lane >> 4;
  const int wm = (wid >> 2) * 128, wn = (wid & 3) * 64;
  const int bid = blockIdx.x;
  const int flat = (bid & 7) * 24 + (bid >> 3);
  const int bx = flat / 12, by = flat % 12;
  const int m0 = bx * 256, n0 = by * 256;
  const char* Ag = (const char*)A + (size_t)m0 * kb;
  const char* Bg = (const char*)Bt + (size_t)n0 * kb;
  char* A0 = smem;
  char* B0 = smem + 65536;
  char* B1 = smem + 98304;
  f32x4 acc[8][4] = {};
  stage_half(Ag, kb, 0, A0, tid);
  stage_half(Ag + 128 * kb, kb, 0, A0 + 16384, tid);
  stage_half(Bg, kb, 0, B0, tid);
  stage_half(Bg + 128 * kb, kb, 0, B0 + 16384, tid);
  stage_half(Bg, kb, 1, B1, tid);
  stage_half(Bg + 128 * kb, kb, 1, B1 + 16384, tid);
  asm volatile("s_waitcnt vmcnt(4)" ::: "memory");
  BAR();
#pragma unroll 1
  for (int i = 0; i < 7; ++i)
    ktile_pair<false>(Ag, Bg, kb, smem, tid, wm, wn, lr, kg, 2 * i + 1,
                      2 * i + 2, 2 * i + 3, acc);
  ktile_pair<true>(Ag, Bg, kb, smem, tid, wm, wn, lr, kg, 15, 16, 17, acc);
#pragma unroll
  for (int nt = 0; nt < 4; ++nt) {
    const int col = n0 + wn + nt * 16 + lr;
    const float bv = bias[col];
#pragma unroll
    for (int mt = 0; mt < 8; ++mt) {
      const int row0 = m0 + wm + mt * 16 + kg * 4;
#pragma unroll
      for (int rr = 0; rr < 4; ++rr)
        C[(size_t)(row0 + rr) * NN + col] = (_Float16)(acc[mt][nt][rr] + bv);
    }
  }
}

// ================= 128x256 8-phase OUT GEMM (fp32 out) =================
template <int Q>
__device__ __forceinline__ void rd_a1(const char* Ab, int wm, int lr, int kg,
                                      f16x8 (&af)[2]) {
  af[0] = ldsfrag(Ab, wm + Q * 16 + lr, kg);
  af[1] = ldsfrag(Ab, wm + Q * 16 + lr, 4 + kg);
}

template <int Q>
__device__ __forceinline__ void do_mfma1(const f16x8 (&af)[2],
                                         const f16x8 (&bf)[4][2],
                                         f32x4 (&acc)[4][4]) {
#pragma unroll
  for (int nt = 0; nt < 4; ++nt) {
    acc[Q][nt] = mfma16(af[0], bf[nt][0], acc[Q][nt]);
    acc[Q][nt] = mfma16(af[1], bf[nt][1], acc[Q][nt]);
  }
}

// LDS: A0 @0 (16K), A1 @16K, B0 @32K (32K), B1 @64K (32K) = 96KB
// stage slots: p0: t1.A->A1 | p1: t2.Bh0->B0 | p2: t2.Bh1->B0 | p3: -
//              p4: t2.A->A0 | p5: t3.Bh0->B1 | p6: t3.Bh1->B1 | p7: -
// vmcnt(4) at end-p3 (retires p0; keeps p1,p2) and end-p7 (retires p1,p2,p4).
template <bool LAST>
__device__ __forceinline__ void ktile_pair_out(const char* Ag, const char* Bg,
                                               size_t kb, char* smem, int tid,
                                               int wm, int wn, int lr, int kg,
                                               int t1, int t2, int t3,
                                               f32x4 (&acc)[4][4]) {
  char* A0 = smem;
  char* A1 = smem + 16384;
  char* B0 = smem + 32768;
  char* B1 = smem + 65536;
  f16x8 bf[4][2], af[2];
  rd_b(B0, wn, lr, kg, bf);
  rd_a1<0>(A0, wm, lr, kg, af);
  stage_half(Ag, kb, t1, A1, tid);
  BAR();
  __builtin_amdgcn_s_setprio(1);
  do_mfma1<0>(af, bf, acc);
  __builtin_amdgcn_s_setprio(0);
  BAR();
  rd_a1<1>(A0, wm, lr, kg, af);
  if (!LAST) stage_half(Bg, kb, t2, B0, tid);
  BAR();
  __builtin_amdgcn_s_setprio(1);
  do_mfma1<1>(af, bf, acc);
  __builtin_amdgcn_s_setprio(0);
  BAR();
  rd_a1<2>(A0, wm, lr, kg, af);
  if (!LAST) stage_half(Bg + 128 * kb, kb, t2, B0 + 16384, tid);
  BAR();
  __builtin_amdgcn_s_setprio(1);
  do_mfma1<2>(af, bf, acc);
  __builtin_amdgcn_s_setprio(0);
  BAR();
  rd_a1<3>(A0, wm, lr, kg, af);
  BAR();
  __builtin_amdgcn_s_setprio(1);
  do_mfma1<3>(af, bf, acc);
  __builtin_amdgcn_s_setprio(0);
  if (LAST)
    asm volatile("s_waitcnt vmcnt(0)" ::: "memory");
  else
    asm volatile("s_waitcnt vmcnt(4)" ::: "memory");
  BAR();
  rd_b(B1, wn, lr, kg, bf);
  rd_a1<0>(A1, wm, lr, kg, af);
  if (!LAST) stage_half(Ag, kb, t2, A0, tid);
  BAR();
  __builtin_amdgcn_s_setprio(1);
  do_mfma1<0>(af, bf, acc);
  __builtin_amdgcn_s_setprio(0);
  BAR();
  rd_a1<1>(A1, wm, lr, kg, af);
  if (!LAST) stage_half(Bg, kb, t3, B1, tid);
  BAR();
  __builtin_amdgcn_s_setprio(1);
  do_mfma1<1>(af, bf, acc);
  __builtin_amdgcn_s_setprio(0);
  BAR();
  rd_a1<2>(A1, wm, lr, kg, af);
  if (!LAST) stage_half(Bg + 128 * kb, kb, t3, B1 + 16384, tid);
  BAR();
  __builtin_amdgcn_s_setprio(1);
  do_mfma1<2>(af, bf, acc);
  __builtin_amdgcn_s_setprio(0);
  BAR();
  rd_a1<3>(A1, wm, lr, kg, af);
  BAR();
  __builtin_amdgcn_s_setprio(1);
  do_mfma1<3>(af, bf, acc);
  __builtin_amdgcn_s_setprio(0);
  if (!LAST) asm volatile("s_waitcnt vmcnt(4)" ::: "memory");
  BAR();
}

__global__ __launch_bounds__(512, 2) void out_gemm256_kernel(
    const _Float16* __restrict__ A, const _Float16* __restrict__ Bt,
    const float* __restrict__ bias, float* __restrict__ C) {
  extern __shared__ char smem[];
  const size_t kb = 2048;
  const int tid = threadIdx.x;
  const int lane = tid & 63, wid = tid >> 6;
  const int lr = lane & 15, kg = lane >> 4;
  const int wm = (wid >> 2) * 64, wn = (wid & 3) * 64;
  const int bid = blockIdx.x;  // 128 blocks: 32 M-tiles x 4 N-tiles
  const int flat = (bid & 7) * 16 + (bid >> 3);
  const int bx = flat >> 2, by = flat & 3;
  const int m0 = bx * 128, n0 = by * 256;
  const char* Ag = (const char*)A + (size_t)m0 * kb;
  const char* Bg = (const char*)Bt + (size_t)n0 * kb;
  char* A0 = smem;
  char* B0 = smem + 32768;
  char* B1 = smem + 65536;
  f32x4 acc[4][4] = {};
  stage_half(Ag, kb, 0, A0, tid);
  stage_half(Bg, kb, 0, B0, tid);
  stage_half(Bg + 128 * kb, kb, 0, B0 + 16384, tid);
  stage_half(Bg, kb, 1, B1, tid);
  stage_half(Bg + 128 * kb, kb, 1, B1 + 16384, tid);
  asm volatile("s_waitcnt vmcnt(4)" ::: "memory");
  BAR();
#pragma unroll 1
  for (int i = 0; i < 7; ++i)
    ktile_pair_out<false>(Ag, Bg, kb, smem, tid, wm, wn, lr, kg, 2 * i + 1,
                          2 * i + 2, 2 * i + 3, acc);
  ktile_pair_out<true>(Ag, Bg, kb, smem, tid, wm, wn, lr, kg, 15, 16, 17, acc);
#pragma unroll
  for (int nt = 0; nt < 4; ++nt) {
    const int col = n0 + wn + nt * 16 + lr;
    const float bv = bias[col];
#pragma unroll
    for (int mt = 0; mt < 4; ++mt) {
      const int row0 = m0 + wm + mt * 16 + kg * 4;
#pragma unroll
      for (int rr = 0; rr < 4; ++rr)
        C[(size_t)(row0 + rr) * 1024 + col] = acc[mt][nt][rr] + bv;
    }
  }
}

// ---------------- permute V into sorted transposed layout Vts[h][d][p] ----------------
__global__ __launch_bounds__(256) void permute_v_kernel(
    const _Float16* __restrict__ qkvh, const int* __restrict__ sorted_idx,
    _Float16* __restrict__ Vts) {
  __shared__ _Float16 vt[64][66];
  const int h = blockIdx.x & 15;
  const int P0 = (blockIdx.x >> 4) * 64;
  const int tid = threadIdx.x;
#pragma unroll
  for (int it = 0; it < 2; ++it) {
    const int i = it * 256 + tid;
    const int row = i >> 3, seg = i & 7;
    const int orig = sorted_idx[P0 + row];
    f16x8 v8 = *(const f16x8*)(qkvh + (size_t)orig * NQKV + 2048 + h * 64 + seg * 8);
#pragma unroll
    for (int e = 0; e < 8; ++e) vt[row][seg * 8 + e] = v8[e];
  }
  __syncthreads();
#pragma unroll
  for (int it = 0; it < 2; ++it) {
    const int i = it * 256 + tid;
    const int d = i >> 3, seg = i & 7;
    f16x8 o;
#pragma unroll
    for (int e = 0; e < 8; ++e) o[e] = vt[seg * 8 + e][d];
    *(f16x8*)(Vts + ((size_t)h * 64 + d) * NSEQ + P0 + seg * 8) = o;
  }
}

// ---------------- fused windowed attention (K,Q gathered from qkvh) ----------------
__global__ __launch_bounds__(256) void attn_kernel(
    const _Float16* __restrict__ qkvh, const _Float16* __restrict__ Vts,
    const unsigned* __restrict__ masks, const int* __restrict__ sorted_idx,
    _Float16* __restrict__ attn_h) {
  __shared__ __align__(128) char sK[32768];  // K window [256][64] f16; later P
  __shared__ __align__(128) char sV[32768];  // Vt window [64][256] f16
  const int b = blockIdx.x, h = blockIdx.y;
  const int tid = threadIdx.x, lane = tid & 63, wid = tid >> 6;
  const int W0 = min(max(64 * b - 96, 0), NSEQ - 256);
  const int lrow16 = lane & 15, kgrp = lane >> 4;
  int ridx[8];
#pragma unroll
  for (int c = 0; c < 8; ++c)
    ridx[c] = sorted_idx[W0 + c * 32 + wid * 8 + (lane >> 3)];
#pragma unroll
  for (int c = 0; c < 8; ++c) {
    const int o = c * 4096 + wid * 1024 + lane * 16;
    const int row = o >> 7;
    const int inrow = (o & 127) ^ ((row & 7) << 4);
    glds16((const char*)qkvh + (size_t)ridx[c] * 6144 + 2048 + h * 128 + inrow,
           sK + o);
    const int d = o >> 9;
    const int inrowv = (o & 511) ^ ((d & 7) << 4);
    glds16((const char*)Vts + (size_t)(h * 64 + d) * (NSEQ * 2) + W0 * 2 + inrowv,
           sV + o);
  }
  const int p_base = b * 64 + wid * 16;
  const int orig_q = sorted_idx[p_base + lrow16];
  const char* qp = (const char*)qkvh + (size_t)orig_q * 6144 + h * 128 + kgrp * 16;
  const f16x8 aq0 = *(const f16x8*)qp;
  const f16x8 aq1 = *(const f16x8*)(qp + 64);
  unsigned mb[4];
#pragma unroll
  for (int r = 0; r < 4; ++r) {
    const int p = p_base + kgrp * 4 + r;
    unsigned bits = 0;
#pragma unroll
    for (int n = 0; n < 16; ++n) {
      const int widx = n * 16 + lrow16;
      bits |= ((masks[p * 8 + (widx >> 5)] >> (widx & 31)) & 1u) << n;
    }
    mb[r] = bits;
  }
  __syncthreads();
  float sv[16][4];
#pragma unroll
  for (int n = 0; n < 16; ++n) {
    const int j = n * 16 + lrow16;
    const int sw = (j & 7) << 4;
    const char* kr = sK + j * 128;
    const f16x8 b0 = *(const f16x8*)(kr + ((kgrp * 16) ^ sw));
    const f16x8 b1 = *(const f16x8*)(kr + ((64 + kgrp * 16) ^ sw));
    f32x4 a = {};
    a = mfma16(aq0, b0, a);
    a = mfma16(aq1, b1, a);
#pragma unroll
    for (int r = 0; r < 4; ++r)
      sv[n][r] = ((mb[r] >> n) & 1u) ? a[r] * 0.125f : -1e30f;
  }
#pragma unroll
  for (int r = 0; r < 4; ++r) {
    float m = sv[0][r];
#pragma unroll
    for (int n = 1; n < 16; ++n) m = fmaxf(m, sv[n][r]);
    m = fmaxf(m, __shfl_xor(m, 1));
    m = fmaxf(m, __shfl_xor(m, 2));
    m = fmaxf(m, __shfl_xor(m, 4));
    m = fmaxf(m, __shfl_xor(m, 8));
    float s = 0.f;
#pragma unroll
    for (int n = 0; n < 16; ++n) {
      const float e = __expf(sv[n][r] - m);
      sv[n][r] = e;
      s += e;
    }
    s += __shfl_xor(s, 1);
    s += __shfl_xor(s, 2);
    s += __shfl_xor(s, 4);
    s += __shfl_xor(s, 8);
    const float rinv = 1.f / s;
#pragma unroll
    for (int n = 0; n < 16; ++n) sv[n][r] *= rinv;
  }
  __syncthreads();
#pragma unroll
  for (int n = 0; n < 16; ++n) {
#pragma unroll
    for (int r = 0; r < 4; ++r) {
      const int lr = wid * 16 + kgrp * 4 + r;
      const int cb = (n * 16 + lrow16) * 2;
      *(_Float16*)(sK + lr * 512 + (cb ^ ((lr & 7) << 4))) = (_Float16)sv[n][r];
    }
  }
  __syncthreads();
  f32x4 oacc[4] = {};
  const int arow = wid * 16 + lrow16;
  const int swa = (arow & 7) << 4;
#pragma unroll
  for (int kt = 0; kt < 8; ++kt) {
    const int kb = kt * 64 + kgrp * 16;
    const f16x8 pa = *(const f16x8*)(sK + arow * 512 + (kb ^ swa));
#pragma unroll
    for (int nt = 0; nt < 4; ++nt) {
      const int d = nt * 16 + lrow16;
      const f16x8 vb = *(const f16x8*)(sV + d * 512 + (kb ^ ((d & 7) << 4)));
      oacc[nt] = mfma16(pa, vb, oacc[nt]);
    }
  }
#pragma unroll
  for (int r = 0; r < 4; ++r) {
    const int p = p_base + kgrp * 4 + r;
    const int orig = sorted_idx[p];
    _Float16* op = attn_h + (size_t)orig * DIMM + h * 64;
#pragma unroll
    for (int nt = 0; nt < 4; ++nt)
      op[nt * 16 + lrow16] = (_Float16)oacc[nt][r];
  }
}

// ---------------- launch ----------------
extern "C" void kernel_launch(void* const* d_in, const int* in_sizes, int n_in,
                              void* d_out, int out_size, void* d_ws, size_t ws_size,
                              hipStream_t stream) {
  const float* x = (const float*)d_in[0];
  const float* cc = (const float*)d_in[1];
  const float* Wqkv = (const float*)d_in[2];
  const float* bqkv = (const float*)d_in[3];
  const float* Wout = (const float*)d_in[4];
  const float* bout = (const float*)d_in[5];
  char* ws = (char*)d_ws;

  _Float16* xh = (_Float16*)(ws + 0);                 //  8 MB
  _Float16* wqkvt = (_Float16*)(ws + 8388608);        //  6 MB
  _Float16* woutt = (_Float16*)(ws + 14680064);       //  2 MB
  _Float16* qkvh = (_Float16*)(ws + 16777216);        // 24 MB
  _Float16* Vtsb = (_Float16*)(ws + 41943040);        //  8 MB
  _Float16* atnh = (_Float16*)(ws + 50331648);        //  8 MB
  int* sidx = (int*)(ws + 58720256);                  // 16 KB
  float* csort = (float*)(ws + 58736640);             // 16 KB
  unsigned* msk = (unsigned*)(ws + 58753024);         // 128 KB

  hipFuncSetAttribute((const void*)qkv_gemm256_kernel,
                      hipFuncAttributeMaxDynamicSharedMemorySize, 131072);
  hipFuncSetAttribute((const void*)out_gemm256_kernel,
                      hipFuncAttributeMaxDynamicSharedMemorySize, 98304);

  convert_x_kernel<<<2048, 256, 0, stream>>>(x, xh);
  transpose_w_kernel<<<dim3(16, 48), 256, 0, stream>>>(Wqkv, wqkvt, 1024, 3072);
  transpose_w_kernel<<<dim3(16, 16), 256, 0, stream>>>(Wout, woutt, 1024, 1024);
  rank_sort_kernel<<<128, 256, 0, stream>>>(cc, sidx, csort);
  mask_kernel<<<1024, 256, 0, stream>>>(csort, sidx, msk);
  qkv_gemm256_kernel<<<192, 512, 131072, stream>>>(xh, wqkvt, bqkv, qkvh);
  permute_v_kernel<<<1024, 256, 0, stream>>>(qkvh, sidx, Vtsb);
  attn_kernel<<<dim3(64, 16), 256, 0, stream>>>(qkvh, Vtsb, msk, sidx, atnh);
  out_gemm256_kernel<<<128, 512, 98304, stream>>>(atnh, woutt, bout,
                                                  (float*)d_out);
}

// Round 5
// 109.753 us; speedup vs baseline: 1.7213x; 1.1460x over previous
//
#include <hip/hip_runtime.h>
#include <hip/hip_bf16.h>

typedef _Float16 f16x8 __attribute__((ext_vector_type(8)));
typedef float f32x4 __attribute__((ext_vector_type(4)));
typedef unsigned long long u64;

#define NSEQ 4096
#define DIMM 1024
#define NHEAD 16
#define HD 64
#define NQKV 3072

#define BAR() asm volatile("s_barrier" ::: "memory")

__device__ __forceinline__ f32x4 mfma16(f16x8 a, f16x8 b, f32x4 c) {
  return __builtin_amdgcn_mfma_f32_16x16x32_f16(a, b, c, 0, 0, 0);
}

__device__ __forceinline__ void glds16(const void* g, void* l) {
  __builtin_amdgcn_global_load_lds(
      (const __attribute__((address_space(1))) void*)g,
      (__attribute__((address_space(3))) void*)l, 16, 0, 0);
}

// ---------------- fused prep: convert_x + 2 transposes + rank_sort ----------------
__global__ __launch_bounds__(256) void prep_kernel(
    const float* __restrict__ x, _Float16* __restrict__ xh,
    const float* __restrict__ Wqkv, _Float16* __restrict__ wqkvt,
    const float* __restrict__ Wout, _Float16* __restrict__ woutt,
    const float* __restrict__ cc, int* __restrict__ sorted_idx,
    float* __restrict__ csort) {
  __shared__ __align__(16) char plds[16640];
  const int bid = blockIdx.x, t = threadIdx.x;
  if (bid < 2048) {
    // x fp32 -> fp16
    const int i = bid * 256 + t;
    const float4 a = ((const float4*)x)[i * 2];
    const float4 b = ((const float4*)x)[i * 2 + 1];
    f16x8 o = {(_Float16)a.x, (_Float16)a.y, (_Float16)a.z, (_Float16)a.w,
               (_Float16)b.x, (_Float16)b.y, (_Float16)b.z, (_Float16)b.w};
    ((f16x8*)xh)[i] = o;
  } else if (bid < 3072) {
    // W [K][Nn] fp32 -> Wt [Nn][K] fp16
    const bool qkv = bid < 2816;
    const int sub = qkv ? bid - 2048 : bid - 2816;
    const float* W = qkv ? Wqkv : Wout;
    _Float16* Wt = qkv ? wqkvt : woutt;
    const int Nn = qkv ? 3072 : 1024;
    const int k0 = (sub & 15) * 64, n0 = (sub >> 4) * 64;
    float (*tile)[65] = (float(*)[65])plds;
    const int tx = t & 63, ty = t >> 6;
    for (int rr = ty; rr < 64; rr += 4)
      tile[rr][tx] = W[(size_t)(k0 + rr) * Nn + n0 + tx];
    __syncthreads();
    for (int ccn = ty; ccn < 64; ccn += 4)
      Wt[(size_t)(n0 + ccn) * 1024 + k0 + tx] = (_Float16)tile[tx][ccn];
  } else {
    // rank sort: exact stable sort by (coord_bits, idx)
    float* sc = (float*)plds;
#pragma unroll
    for (int it = 0; it < 4; ++it) {
      const int i = it * 256 + t;
      ((float4*)sc)[i] = ((const float4*)cc)[i];
    }
    __syncthreads();
    const int elem = (bid - 3072) * 32 + (t >> 3);
    const int s = t & 7;
    const unsigned mybits = __float_as_uint(sc[elem]);
    int cnt = 0;
#pragma unroll 8
    for (int m = 0; m < 512; ++m) {
      const int j = s + (m << 3);
      const unsigned bj = __float_as_uint(sc[j]);
      cnt += (bj < mybits || (bj == mybits && j < elem)) ? 1 : 0;
    }
    cnt += __shfl_xor(cnt, 1);
    cnt += __shfl_xor(cnt, 2);
    cnt += __shfl_xor(cnt, 4);
    if (s == 0) {
      sorted_idx[cnt] = elem;
      csort[cnt] = sc[elem];
    }
  }
}

// ---------------- per-query exact top-64 -> 256-bit window mask ----------------
__global__ __launch_bounds__(256) void mask_kernel(
    const float* __restrict__ csort, const int* __restrict__ sorted_idx,
    unsigned* __restrict__ masks) {
  __shared__ unsigned lm[4][8];
  const int tid = threadIdx.x, lane = tid & 63, wid = tid >> 6;
  const int p = blockIdx.x * 4 + wid;
  int W0 = 64 * (p >> 6) - 96;
  W0 = min(max(W0, 0), NSEQ - 256);
  const float cp = csort[p];
  u64 key[4];
#pragma unroll
  for (int r = 0; r < 4; ++r) {
    const int w = r * 64 + lane;
    const float d = fabsf(csort[W0 + w] - cp);
    key[r] = (((u64)__float_as_uint(d)) << 20) |
             (((u64)(unsigned)sorted_idx[W0 + w]) << 8) | (unsigned)w;
  }
  if (lane < 8) lm[wid][lane] = 0u;
#pragma unroll
  for (int k = 2; k <= 256; k <<= 1) {
#pragma unroll
    for (int j = k >> 1; j > 0; j >>= 1) {
      if (j >= 64) {
        const int rj = j >> 6;
#pragma unroll
        for (int r = 0; r < 4; ++r) {
          const int rp = r ^ rj;
          if (rp > r) {
            const bool up = (((r * 64) & k) == 0);
            const u64 a = key[r], b2 = key[rp];
            const bool sw = (a > b2) == up;
            key[r] = sw ? b2 : a;
            key[rp] = sw ? a : b2;
          }
        }
      } else {
#pragma unroll
        for (int r = 0; r < 4; ++r) {
          const u64 pv = __shfl_xor(key[r], j);
          const bool up = (((r * 64 + lane) & k) == 0);
          const bool lower = ((lane & j) == 0);
          const bool takemin = (lower == up);
          const u64 mn = key[r] < pv ? key[r] : pv;
          const u64 mx = key[r] < pv ? pv : key[r];
          key[r] = takemin ? mn : mx;
        }
      }
    }
  }
  const unsigned w0 = (unsigned)(key[0] & 0xffu);
  atomicOr(&lm[wid][w0 >> 5], 1u << (w0 & 31u));
  __syncthreads();
  if (lane < 8) masks[p * 8 + lane] = lm[wid][lane];
}

// ================= shared GEMM helpers =================
__device__ __forceinline__ f16x8 ldsfrag(const char* base, int r, int g) {
  return *(const f16x8*)(base + r * 128 + ((g ^ (r & 7)) << 4));
}

// stage 128 rows x 64 cols f16 (16KB): 2 glds16/thread (512 threads).
__device__ __forceinline__ void stage_half(const char* gbase, size_t kb, int t,
                                           char* lds_half, int tid) {
#pragma unroll
  for (int s = 0; s < 2; ++s) {
    const int rel = tid * 16 + s * 8192;
    const int r = rel >> 7;
    const int g = (rel >> 4) & 7;
    const int gg = g ^ (r & 7);
    glds16(gbase + (size_t)r * kb + t * 128 + gg * 16, lds_half + rel);
  }
}

// stage 64 rows x 64 cols f16 (8KB): 1 glds16/thread (512 threads).
__device__ __forceinline__ void stage_64r(const char* gbase, size_t kb, int t,
                                          char* lds8k, int tid) {
  const int rel = tid * 16;
  const int r = rel >> 7;
  const int g = (rel >> 4) & 7;
  const int gg = g ^ (r & 7);
  glds16(gbase + (size_t)r * kb + t * 128 + gg * 16, lds8k + rel);
}

// ================= 256x192 8-phase QKV GEMM (grid 256 = 16x16) =================
__device__ __forceinline__ void rd_b3(const char* Bb, int wn, int lr, int kg,
                                      f16x8 (&bf)[3][2]) {
#pragma unroll
  for (int nt = 0; nt < 3; ++nt) {
    bf[nt][0] = ldsfrag(Bb, wn + nt * 16 + lr, kg);
    bf[nt][1] = ldsfrag(Bb, wn + nt * 16 + lr, 4 + kg);
  }
}

template <int Q>
__device__ __forceinline__ void rd_a(const char* Ab, int wm, int lr, int kg,
                                     f16x8 (&af)[2][2]) {
#pragma unroll
  for (int m = 0; m < 2; ++m) {
    af[m][0] = ldsfrag(Ab, wm + (2 * Q + m) * 16 + lr, kg);
    af[m][1] = ldsfrag(Ab, wm + (2 * Q + m) * 16 + lr, 4 + kg);
  }
}

template <int Q>
__device__ __forceinline__ void do_mfma3(const f16x8 (&af)[2][2],
                                         const f16x8 (&bf)[3][2],
                                         f32x4 (&acc)[8][3]) {
#pragma unroll
  for (int m = 0; m < 2; ++m)
#pragma unroll
    for (int nt = 0; nt < 3; ++nt) {
      acc[2 * Q + m][nt] = mfma16(af[m][0], bf[nt][0], acc[2 * Q + m][nt]);
      acc[2 * Q + m][nt] = mfma16(af[m][1], bf[nt][1], acc[2 * Q + m][nt]);
    }
}

// A units: 4x64 rows; B units: 3x64 rows. Stage ledger (1 load/unit/thread):
//  p0/p1: odd A (4u) -> A1 ; p2/p3: next-even B (3u) -> B0 ; vmcnt(3) @p3
//  p4/p5: next-even A (4u) -> A0 ; p6/p7: next-odd B (3u) -> B1 ; vmcnt(3) @p7
template <bool LAST>
__device__ __forceinline__ void ktile_pair192(const char* Ag, const char* Bg,
                                              size_t kb, char* smem, int tid,
                                              int wm, int wn, int lr, int kg,
                                              int t1, int t2, int t3,
                                              f32x4 (&acc)[8][3]) {
  char* A0 = smem;
  char* A1 = smem + 32768;
  char* B0 = smem + 65536;
  char* B1 = smem + 65536 + 24576;
  f16x8 bf[3][2], af[2][2];
  rd_b3(B0, wn, lr, kg, bf);
  rd_a<0>(A0, wm, lr, kg, af);
  stage_64r(Ag, kb, t1, A1, tid);
  stage_64r(Ag + 64 * kb, kb, t1, A1 + 8192, tid);
  BAR();
  __builtin_amdgcn_s_setprio(1);
  do_mfma3<0>(af, bf, acc);
  __builtin_amdgcn_s_setprio(0);
  BAR();
  rd_a<1>(A0, wm, lr, kg, af);
  stage_64r(Ag + 128 * kb, kb, t1, A1 + 16384, tid);
  stage_64r(Ag + 192 * kb, kb, t1, A1 + 24576, tid);
  BAR();
  __builtin_amdgcn_s_setprio(1);
  do_mfma3<1>(af, bf, acc);
  __builtin_amdgcn_s_setprio(0);
  BAR();
  rd_a<2>(A0, wm, lr, kg, af);
  if (!LAST) {
    stage_64r(Bg, kb, t2, B0, tid);
    stage_64r(Bg + 64 * kb, kb, t2, B0 + 8192, tid);
  }
  BAR();
  __builtin_amdgcn_s_setprio(1);
  do_mfma3<2>(af, bf, acc);
  __builtin_amdgcn_s_setprio(0);
  BAR();
  rd_a<3>(A0, wm, lr, kg, af);
  if (!LAST) stage_64r(Bg + 128 * kb, kb, t2, B0 + 16384, tid);
  BAR();
  __builtin_amdgcn_s_setprio(1);
  do_mfma3<3>(af, bf, acc);
  __builtin_amdgcn_s_setprio(0);
  if (LAST)
    asm volatile("s_waitcnt vmcnt(0)" ::: "memory");
  else
    asm volatile("s_waitcnt vmcnt(3)" ::: "memory");
  BAR();
  rd_b3(B1, wn, lr, kg, bf);
  rd_a<0>(A1, wm, lr, kg, af);
  if (!LAST) {
    stage_64r(Ag, kb, t2, A0, tid);
    stage_64r(Ag + 64 * kb, kb, t2, A0 + 8192, tid);
  }
  BAR();
  __builtin_amdgcn_s_setprio(1);
  do_mfma3<0>(af, bf, acc);
  __builtin_amdgcn_s_setprio(0);
  BAR();
  rd_a<1>(A1, wm, lr, kg, af);
  if (!LAST) {
    stage_64r(Ag + 128 * kb, kb, t2, A0 + 16384, tid);
    stage_64r(Ag + 192 * kb, kb, t2, A0 + 24576, tid);
  }
  BAR();
  __builtin_amdgcn_s_setprio(1);
  do_mfma3<1>(af, bf, acc);
  __builtin_amdgcn_s_setprio(0);
  BAR();
  rd_a<2>(A1, wm, lr, kg, af);
  if (!LAST) {
    stage_64r(Bg, kb, t3, B1, tid);
    stage_64r(Bg + 64 * kb, kb, t3, B1 + 8192, tid);
  }
  BAR();
  __builtin_amdgcn_s_setprio(1);
  do_mfma3<2>(af, bf, acc);
  __builtin_amdgcn_s_setprio(0);
  BAR();
  rd_a<3>(A1, wm, lr, kg, af);
  if (!LAST) stage_64r(Bg + 128 * kb, kb, t3, B1 + 16384, tid);
  BAR();
  __builtin_amdgcn_s_setprio(1);
  do_mfma3<3>(af, bf, acc);
  __builtin_amdgcn_s_setprio(0);
  if (!LAST) asm volatile("s_waitcnt vmcnt(3)" ::: "memory");
  BAR();
}

__global__ __launch_bounds__(512, 2) void qkv_gemm192_kernel(
    const _Float16* __restrict__ A, const _Float16* __restrict__ Bt,
    const float* __restrict__ bias, _Float16* __restrict__ C) {
  extern __shared__ char smem[];
  const int NN = 3072;
  const size_t kb = 2048;
  const int tid = threadIdx.x;
  const int lane = tid & 63, wid = tid >> 6;
  const int lr = lane & 15, kg = lane >> 4;
  const int wm = (wid >> 2) * 128, wn = (wid & 3) * 48;
  const int bid = blockIdx.x;  // 256 blocks: 16 M x 16 N
  const int flat = (bid & 7) * 32 + (bid >> 3);
  const int bx = flat >> 4, by = flat & 15;
  const int m0 = bx * 256, n0 = by * 192;
  const char* Ag = (const char*)A + (size_t)m0 * kb;
  const char* Bg = (const char*)Bt + (size_t)n0 * kb;
  char* A0 = smem;
  char* B0 = smem + 65536;
  char* B1 = smem + 65536 + 24576;
  f32x4 acc[8][3] = {};
  // prologue: t0 A (4u) + t0 B (3u) + t1 B (3u); keep newest 3 in flight
#pragma unroll
  for (int u = 0; u < 4; ++u)
    stage_64r(Ag + (size_t)(64 * u) * kb, kb, 0, A0 + u * 8192, tid);
#pragma unroll
  for (int u = 0; u < 3; ++u)
    stage_64r(Bg + (size_t)(64 * u) * kb, kb, 0, B0 + u * 8192, tid);
#pragma unroll
  for (int u = 0; u < 3; ++u)
    stage_64r(Bg + (size_t)(64 * u) * kb, kb, 1, B1 + u * 8192, tid);
  asm volatile("s_waitcnt vmcnt(3)" ::: "memory");
  BAR();
#pragma unroll 1
  for (int i = 0; i < 7; ++i)
    ktile_pair192<false>(Ag, Bg, kb, smem, tid, wm, wn, lr, kg, 2 * i + 1,
                         2 * i + 2, 2 * i + 3, acc);
  ktile_pair192<true>(Ag, Bg, kb, smem, tid, wm, wn, lr, kg, 15, 16, 17, acc);
#pragma unroll
  for (int nt = 0; nt < 3; ++nt) {
    const int col = n0 + wn + nt * 16 + lr;
    const float bv = bias[col];
#pragma unroll
    for (int mt = 0; mt < 8; ++mt) {
      const int row0 = m0 + wm + mt * 16 + kg * 4;
#pragma unroll
      for (int rr = 0; rr < 4; ++rr)
        C[(size_t)(row0 + rr) * NN + col] = (_Float16)(acc[mt][nt][rr] + bv);
    }
  }
}

// ================= 128x128 triple-buffered OUT GEMM (grid 256 = 32x8) =================
__global__ __launch_bounds__(512, 2) void out_gemm128_kernel(
    const _Float16* __restrict__ A, const _Float16* __restrict__ Bt,
    const float* __restrict__ bias, float* __restrict__ C) {
  extern __shared__ char smem[];  // A0/A1/A2 @0/16K/32K, B0/B1/B2 @48K/64K/80K
  const size_t kb = 2048;
  const int tid = threadIdx.x;
  const int lane = tid & 63, wid = tid >> 6;
  const int lr = lane & 15, kg = lane >> 4;
  const int wm = (wid >> 2) * 64, wn = (wid & 3) * 32;
  const int bid = blockIdx.x;  // 256 blocks: 32 M x 8 N
  const int flat = (bid & 7) * 32 + (bid >> 3);
  const int bx = flat >> 3, by = flat & 7;
  const int m0 = bx * 128, n0 = by * 128;
  const char* Ag = (const char*)A + (size_t)m0 * kb;
  const char* Bg = (const char*)Bt + (size_t)n0 * kb;
  f32x4 acc[4][2] = {};
  // prologue: tiles 0,1
  stage_half(Ag, kb, 0, smem, tid);
  stage_half(Bg, kb, 0, smem + 49152, tid);
  stage_half(Ag, kb, 1, smem + 16384, tid);
  stage_half(Bg, kb, 1, smem + 49152 + 16384, tid);
  asm volatile("s_waitcnt vmcnt(4)" ::: "memory");
  BAR();
#pragma unroll
  for (int t = 0; t < 16; ++t) {
    const char* At = smem + (t % 3) * 16384;
    const char* Bb = smem + 49152 + (t % 3) * 16384;
    f16x8 bf[2][2], af[4][2];
#pragma unroll
    for (int nt = 0; nt < 2; ++nt) {
      bf[nt][0] = ldsfrag(Bb, wn + nt * 16 + lr, kg);
      bf[nt][1] = ldsfrag(Bb, wn + nt * 16 + lr, 4 + kg);
    }
#pragma unroll
    for (int m = 0; m < 4; ++m) {
      af[m][0] = ldsfrag(At, wm + m * 16 + lr, kg);
      af[m][1] = ldsfrag(At, wm + m * 16 + lr, 4 + kg);
    }
    if (t < 14) {
      stage_half(Ag, kb, t + 2, smem + ((t + 2) % 3) * 16384, tid);
      stage_half(Bg, kb, t + 2, smem + 49152 + ((t + 2) % 3) * 16384, tid);
    }
    BAR();
    __builtin_amdgcn_s_setprio(1);
#pragma unroll
    for (int m = 0; m < 4; ++m)
#pragma unroll
      for (int nt = 0; nt < 2; ++nt) {
        acc[m][nt] = mfma16(af[m][0], bf[nt][0], acc[m][nt]);
        acc[m][nt] = mfma16(af[m][1], bf[nt][1], acc[m][nt]);
      }
    __builtin_amdgcn_s_setprio(0);
    if (t < 14)
      asm volatile("s_waitcnt vmcnt(4)" ::: "memory");
    else if (t == 14)
      asm volatile("s_waitcnt vmcnt(0)" ::: "memory");
    BAR();
  }
#pragma unroll
  for (int nt = 0; nt < 2; ++nt) {
    const int col = n0 + wn + nt * 16 + lr;
    const float bv = bias[col];
#pragma unroll
    for (int mt = 0; mt < 4; ++mt) {
      const int row0 = m0 + wm + mt * 16 + kg * 4;
#pragma unroll
      for (int rr = 0; rr < 4; ++rr)
        C[(size_t)(row0 + rr) * 1024 + col] = acc[mt][nt][rr] + bv;
    }
  }
}

// ---------------- permute V into sorted transposed layout Vts[h][d][p] ----------------
__global__ __launch_bounds__(256) void permute_v_kernel(
    const _Float16* __restrict__ qkvh, const int* __restrict__ sorted_idx,
    _Float16* __restrict__ Vts) {
  __shared__ _Float16 vt[64][66];
  const int h = blockIdx.x & 15;
  const int P0 = (blockIdx.x >> 4) * 64;
  const int tid = threadIdx.x;
#pragma unroll
  for (int it = 0; it < 2; ++it) {
    const int i = it * 256 + tid;
    const int row = i >> 3, seg = i & 7;
    const int orig = sorted_idx[P0 + row];
    f16x8 v8 = *(const f16x8*)(qkvh + (size_t)orig * NQKV + 2048 + h * 64 + seg * 8);
#pragma unroll
    for (int e = 0; e < 8; ++e) vt[row][seg * 8 + e] = v8[e];
  }
  __syncthreads();
#pragma unroll
  for (int it = 0; it < 2; ++it) {
    const int i = it * 256 + tid;
    const int d = i >> 3, seg = i & 7;
    f16x8 o;
#pragma unroll
    for (int e = 0; e < 8; ++e) o[e] = vt[seg * 8 + e][d];
    *(f16x8*)(Vts + ((size_t)h * 64 + d) * NSEQ + P0 + seg * 8) = o;
  }
}

// ---------------- fused windowed attention ----------------
__global__ __launch_bounds__(256) void attn_kernel(
    const _Float16* __restrict__ qkvh, const _Float16* __restrict__ Vts,
    const unsigned* __restrict__ masks, const int* __restrict__ sorted_idx,
    _Float16* __restrict__ attn_h) {
  __shared__ __align__(128) char sK[32768];  // K window [256][64] f16; later P
  __shared__ __align__(128) char sV[32768];  // Vt window [64][256] f16
  // XCD swizzle: adjacent windows (which share 192/256 K rows) on same XCD
  const int flat = (blockIdx.x & 7) * 128 + (blockIdx.x >> 3);
  const int b = flat & 63, h = flat >> 6;
  const int tid = threadIdx.x, lane = tid & 63, wid = tid >> 6;
  const int W0 = min(max(64 * b - 96, 0), NSEQ - 256);
  const int lrow16 = lane & 15, kgrp = lane >> 4;
  int ridx[8];
#pragma unroll
  for (int c = 0; c < 8; ++c)
    ridx[c] = sorted_idx[W0 + c * 32 + wid * 8 + (lane >> 3)];
#pragma unroll
  for (int c = 0; c < 8; ++c) {
    const int o = c * 4096 + wid * 1024 + lane * 16;
    const int row = o >> 7;
    const int inrow = (o & 127) ^ ((row & 7) << 4);
    glds16((const char*)qkvh + (size_t)ridx[c] * 6144 + 2048 + h * 128 + inrow,
           sK + o);
    const int d = o >> 9;
    const int inrowv = (o & 511) ^ ((d & 7) << 4);
    glds16((const char*)Vts + (size_t)(h * 64 + d) * (NSEQ * 2) + W0 * 2 + inrowv,
           sV + o);
  }
  const int p_base = b * 64 + wid * 16;
  const int orig_q = sorted_idx[p_base + lrow16];
  const char* qp = (const char*)qkvh + (size_t)orig_q * 6144 + h * 128 + kgrp * 16;
  const f16x8 aq0 = *(const f16x8*)qp;
  const f16x8 aq1 = *(const f16x8*)(qp + 64);
  unsigned mb[4];
#pragma unroll
  for (int r = 0; r < 4; ++r) {
    const int p = p_base + kgrp * 4 + r;
    unsigned bits = 0;
#pragma unroll
    for (int n = 0; n < 16; ++n) {
      const int widx = n * 16 + lrow16;
      bits |= ((masks[p * 8 + (widx >> 5)] >> (widx & 31)) & 1u) << n;
    }
    mb[r] = bits;
  }
  __syncthreads();
  float sv[16][4];
#pragma unroll
  for (int n = 0; n < 16; ++n) {
    const int j = n * 16 + lrow16;
    const int sw = (j & 7) << 4;
    const char* kr = sK + j * 128;
    const f16x8 b0 = *(const f16x8*)(kr + ((kgrp * 16) ^ sw));
    const f16x8 b1 = *(const f16x8*)(kr + ((64 + kgrp * 16) ^ sw));
    f32x4 a = {};
    a = mfma16(aq0, b0, a);
    a = mfma16(aq1, b1, a);
#pragma unroll
    for (int r = 0; r < 4; ++r)
      sv[n][r] = ((mb[r] >> n) & 1u) ? a[r] * 0.125f : -1e30f;
  }
#pragma unroll
  for (int r = 0; r < 4; ++r) {
    float m = sv[0][r];
#pragma unroll
    for (int n = 1; n < 16; ++n) m = fmaxf(m, sv[n][r]);
    m = fmaxf(m, __shfl_xor(m, 1));
    m = fmaxf(m, __shfl_xor(m, 2));
    m = fmaxf(m, __shfl_xor(m, 4));
    m = fmaxf(m, __shfl_xor(m, 8));
    float s = 0.f;
#pragma unroll
    for (int n = 0; n < 16; ++n) {
      const float e = __expf(sv[n][r] - m);
      sv[n][r] = e;
      s += e;
    }
    s += __shfl_xor(s, 1);
    s += __shfl_xor(s, 2);
    s += __shfl_xor(s, 4);
    s += __shfl_xor(s, 8);
    const float rinv = 1.f / s;
#pragma unroll
    for (int n = 0; n < 16; ++n) sv[n][r] *= rinv;
  }
  __syncthreads();
#pragma unroll
  for (int n = 0; n < 16; ++n) {
#pragma unroll
    for (int r = 0; r < 4; ++r) {
      const int lr = wid * 16 + kgrp * 4 + r;
      const int cb = (n * 16 + lrow16) * 2;
      *(_Float16*)(sK + lr * 512 + (cb ^ ((lr & 7) << 4))) = (_Float16)sv[n][r];
    }
  }
  __syncthreads();
  f32x4 oacc[4] = {};
  const int arow = wid * 16 + lrow16;
  const int swa = (arow & 7) << 4;
#pragma unroll
  for (int kt = 0; kt < 8; ++kt) {
    const int kbo = kt * 64 + kgrp * 16;
    const f16x8 pa = *(const f16x8*)(sK + arow * 512 + (kbo ^ swa));
#pragma unroll
    for (int nt = 0; nt < 4; ++nt) {
      const int d = nt * 16 + lrow16;
      const f16x8 vb = *(const f16x8*)(sV + d * 512 + (kbo ^ ((d & 7) << 4)));
      oacc[nt] = mfma16(pa, vb, oacc[nt]);
    }
  }
#pragma unroll
  for (int r = 0; r < 4; ++r) {
    const int p = p_base + kgrp * 4 + r;
    const int orig = sorted_idx[p];
    _Float16* op = attn_h + (size_t)orig * DIMM + h * 64;
#pragma unroll
    for (int nt = 0; nt < 4; ++nt)
      op[nt * 16 + lrow16] = (_Float16)oacc[nt][r];
  }
}

// ---------------- launch ----------------
extern "C" void kernel_launch(void* const* d_in, const int* in_sizes, int n_in,
                              void* d_out, int out_size, void* d_ws, size_t ws_size,
                              hipStream_t stream) {
  const float* x = (const float*)d_in[0];
  const float* cc = (const float*)d_in[1];
  const float* Wqkv = (const float*)d_in[2];
  const float* bqkv = (const float*)d_in[3];
  const float* Wout = (const float*)d_in[4];
  const float* bout = (const float*)d_in[5];
  char* ws = (char*)d_ws;

  _Float16* xh = (_Float16*)(ws + 0);                 //  8 MB
  _Float16* wqkvt = (_Float16*)(ws + 8388608);        //  6 MB
  _Float16* woutt = (_Float16*)(ws + 14680064);       //  2 MB
  _Float16* qkvh = (_Float16*)(ws + 16777216);        // 24 MB
  _Float16* Vtsb = (_Float16*)(ws + 41943040);        //  8 MB
  _Float16* atnh = (_Float16*)(ws + 50331648);        //  8 MB
  int* sidx = (int*)(ws + 58720256);                  // 16 KB
  float* csort = (float*)(ws + 58736640);             // 16 KB
  unsigned* msk = (unsigned*)(ws + 58753024);         // 128 KB

  hipFuncSetAttribute((const void*)qkv_gemm192_kernel,
                      hipFuncAttributeMaxDynamicSharedMemorySize, 114688);
  hipFuncSetAttribute((const void*)out_gemm128_kernel,
                      hipFuncAttributeMaxDynamicSharedMemorySize, 98304);

  prep_kernel<<<3200, 256, 0, stream>>>(x, xh, Wqkv, wqkvt, Wout, woutt, cc,
                                        sidx, csort);
  mask_kernel<<<1024, 256, 0, stream>>>(csort, sidx, msk);
  qkv_gemm192_kernel<<<256, 512, 114688, stream>>>(xh, wqkvt, bqkv, qkvh);
  permute_v_kernel<<<1024, 256, 0, stream>>>(qkvh, sidx, Vtsb);
  attn_kernel<<<1024, 256, 0, stream>>>(qkvh, Vtsb, msk, sidx, atnh);
  out_gemm128_kernel<<<256, 512, 98304, stream>>>(atnh, woutt, bout,
                                                  (float*)d_out);
}

// Round 6
// 109.617 us; speedup vs baseline: 1.7234x; 1.0012x over previous
//
#include <hip/hip_runtime.h>
#include <hip/hip_bf16.h>

typedef _Float16 f16x8 __attribute__((ext_vector_type(8)));
typedef float f32x4 __attribute__((ext_vector_type(4)));
typedef unsigned long long u64;

#define NSEQ 4096
#define DIMM 1024
#define NHEAD 16
#define HD 64
#define NQKV 3072

#define BAR() asm volatile("s_barrier" ::: "memory")

__device__ __forceinline__ f32x4 mfma16(f16x8 a, f16x8 b, f32x4 c) {
  return __builtin_amdgcn_mfma_f32_16x16x32_f16(a, b, c, 0, 0, 0);
}

__device__ __forceinline__ void glds16(const void* g, void* l) {
  __builtin_amdgcn_global_load_lds(
      (const __attribute__((address_space(1))) void*)g,
      (__attribute__((address_space(3))) void*)l, 16, 0, 0);
}

// ---------------- fused prep: convert_x + 2 transposes + rank_sort ----------------
__global__ __launch_bounds__(256) void prep_kernel(
    const float* __restrict__ x, _Float16* __restrict__ xh,
    const float* __restrict__ Wqkv, _Float16* __restrict__ wqkvt,
    const float* __restrict__ Wout, _Float16* __restrict__ woutt,
    const float* __restrict__ cc, int* __restrict__ sorted_idx,
    float* __restrict__ csort) {
  __shared__ __align__(16) char plds[16640];
  const int bid = blockIdx.x, t = threadIdx.x;
  if (bid < 2048) {
    const int i = bid * 256 + t;
    const float4 a = ((const float4*)x)[i * 2];
    const float4 b = ((const float4*)x)[i * 2 + 1];
    f16x8 o = {(_Float16)a.x, (_Float16)a.y, (_Float16)a.z, (_Float16)a.w,
               (_Float16)b.x, (_Float16)b.y, (_Float16)b.z, (_Float16)b.w};
    ((f16x8*)xh)[i] = o;
  } else if (bid < 3072) {
    const bool qkv = bid < 2816;
    const int sub = qkv ? bid - 2048 : bid - 2816;
    const float* W = qkv ? Wqkv : Wout;
    _Float16* Wt = qkv ? wqkvt : woutt;
    const int Nn = qkv ? 3072 : 1024;
    const int k0 = (sub & 15) * 64, n0 = (sub >> 4) * 64;
    float (*tile)[65] = (float(*)[65])plds;
    const int tx = t & 63, ty = t >> 6;
    for (int rr = ty; rr < 64; rr += 4)
      tile[rr][tx] = W[(size_t)(k0 + rr) * Nn + n0 + tx];
    __syncthreads();
    for (int ccn = ty; ccn < 64; ccn += 4)
      Wt[(size_t)(n0 + ccn) * 1024 + k0 + tx] = (_Float16)tile[tx][ccn];
  } else {
    float* sc = (float*)plds;
#pragma unroll
    for (int it = 0; it < 4; ++it) {
      const int i = it * 256 + t;
      ((float4*)sc)[i] = ((const float4*)cc)[i];
    }
    __syncthreads();
    const int elem = (bid - 3072) * 32 + (t >> 3);
    const int s = t & 7;
    const unsigned mybits = __float_as_uint(sc[elem]);
    int cnt = 0;
#pragma unroll 8
    for (int m = 0; m < 512; ++m) {
      const int j = s + (m << 3);
      const unsigned bj = __float_as_uint(sc[j]);
      cnt += (bj < mybits || (bj == mybits && j < elem)) ? 1 : 0;
    }
    cnt += __shfl_xor(cnt, 1);
    cnt += __shfl_xor(cnt, 2);
    cnt += __shfl_xor(cnt, 4);
    if (s == 0) {
      sorted_idx[cnt] = elem;
      csort[cnt] = sc[elem];
    }
  }
}

// ---------------- per-query exact top-64 -> 256-bit window mask ----------------
__global__ __launch_bounds__(256) void mask_kernel(
    const float* __restrict__ csort, const int* __restrict__ sorted_idx,
    unsigned* __restrict__ masks) {
  __shared__ unsigned lm[4][8];
  const int tid = threadIdx.x, lane = tid & 63, wid = tid >> 6;
  const int p = blockIdx.x * 4 + wid;
  int W0 = 64 * (p >> 6) - 96;
  W0 = min(max(W0, 0), NSEQ - 256);
  const float cp = csort[p];
  u64 key[4];
#pragma unroll
  for (int r = 0; r < 4; ++r) {
    const int w = r * 64 + lane;
    const float d = fabsf(csort[W0 + w] - cp);
    key[r] = (((u64)__float_as_uint(d)) << 20) |
             (((u64)(unsigned)sorted_idx[W0 + w]) << 8) | (unsigned)w;
  }
  if (lane < 8) lm[wid][lane] = 0u;
#pragma unroll
  for (int k = 2; k <= 256; k <<= 1) {
#pragma unroll
    for (int j = k >> 1; j > 0; j >>= 1) {
      if (j >= 64) {
        const int rj = j >> 6;
#pragma unroll
        for (int r = 0; r < 4; ++r) {
          const int rp = r ^ rj;
          if (rp > r) {
            const bool up = (((r * 64) & k) == 0);
            const u64 a = key[r], b2 = key[rp];
            const bool sw = (a > b2) == up;
            key[r] = sw ? b2 : a;
            key[rp] = sw ? a : b2;
          }
        }
      } else {
#pragma unroll
        for (int r = 0; r < 4; ++r) {
          const u64 pv = __shfl_xor(key[r], j);
          const bool up = (((r * 64 + lane) & k) == 0);
          const bool lower = ((lane & j) == 0);
          const bool takemin = (lower == up);
          const u64 mn = key[r] < pv ? key[r] : pv;
          const u64 mx = key[r] < pv ? pv : key[r];
          key[r] = takemin ? mn : mx;
        }
      }
    }
  }
  const unsigned w0 = (unsigned)(key[0] & 0xffu);
  atomicOr(&lm[wid][w0 >> 5], 1u << (w0 & 31u));
  __syncthreads();
  if (lane < 8) masks[p * 8 + lane] = lm[wid][lane];
}

// ================= shared GEMM helpers =================
__device__ __forceinline__ f16x8 ldsfrag(const char* base, int r, int g) {
  return *(const f16x8*)(base + r * 128 + ((g ^ (r & 7)) << 4));
}

__device__ __forceinline__ void stage_half(const char* gbase, size_t kb, int t,
                                           char* lds_half, int tid) {
#pragma unroll
  for (int s = 0; s < 2; ++s) {
    const int rel = tid * 16 + s * 8192;
    const int r = rel >> 7;
    const int g = (rel >> 4) & 7;
    const int gg = g ^ (r & 7);
    glds16(gbase + (size_t)r * kb + t * 128 + gg * 16, lds_half + rel);
  }
}

__device__ __forceinline__ void stage_64r(const char* gbase, size_t kb, int t,
                                          char* lds8k, int tid) {
  const int rel = tid * 16;
  const int r = rel >> 7;
  const int g = (rel >> 4) & 7;
  const int gg = g ^ (r & 7);
  glds16(gbase + (size_t)r * kb + t * 128 + gg * 16, lds8k + rel);
}

// ================= 256x192 8-phase QKV GEMM (grid 256 = 16x16) =================
__device__ __forceinline__ void rd_b3(const char* Bb, int wn, int lr, int kg,
                                      f16x8 (&bf)[3][2]) {
#pragma unroll
  for (int nt = 0; nt < 3; ++nt) {
    bf[nt][0] = ldsfrag(Bb, wn + nt * 16 + lr, kg);
    bf[nt][1] = ldsfrag(Bb, wn + nt * 16 + lr, 4 + kg);
  }
}

template <int Q>
__device__ __forceinline__ void rd_a(const char* Ab, int wm, int lr, int kg,
                                     f16x8 (&af)[2][2]) {
#pragma unroll
  for (int m = 0; m < 2; ++m) {
    af[m][0] = ldsfrag(Ab, wm + (2 * Q + m) * 16 + lr, kg);
    af[m][1] = ldsfrag(Ab, wm + (2 * Q + m) * 16 + lr, 4 + kg);
  }
}

template <int Q>
__device__ __forceinline__ void do_mfma3(const f16x8 (&af)[2][2],
                                         const f16x8 (&bf)[3][2],
                                         f32x4 (&acc)[8][3]) {
#pragma unroll
  for (int m = 0; m < 2; ++m)
#pragma unroll
    for (int nt = 0; nt < 3; ++nt) {
      acc[2 * Q + m][nt] = mfma16(af[m][0], bf[nt][0], acc[2 * Q + m][nt]);
      acc[2 * Q + m][nt] = mfma16(af[m][1], bf[nt][1], acc[2 * Q + m][nt]);
    }
}

template <bool LAST>
__device__ __forceinline__ void ktile_pair192(const char* Ag, const char* Bg,
                                              size_t kb, char* smem, int tid,
                                              int wm, int wn, int lr, int kg,
                                              int t1, int t2, int t3,
                                              f32x4 (&acc)[8][3]) {
  char* A0 = smem;
  char* A1 = smem + 32768;
  char* B0 = smem + 65536;
  char* B1 = smem + 65536 + 24576;
  f16x8 bf[3][2], af[2][2];
  rd_b3(B0, wn, lr, kg, bf);
  rd_a<0>(A0, wm, lr, kg, af);
  stage_64r(Ag, kb, t1, A1, tid);
  stage_64r(Ag + 64 * kb, kb, t1, A1 + 8192, tid);
  BAR();
  __builtin_amdgcn_s_setprio(1);
  do_mfma3<0>(af, bf, acc);
  __builtin_amdgcn_s_setprio(0);
  BAR();
  rd_a<1>(A0, wm, lr, kg, af);
  stage_64r(Ag + 128 * kb, kb, t1, A1 + 16384, tid);
  stage_64r(Ag + 192 * kb, kb, t1, A1 + 24576, tid);
  BAR();
  __builtin_amdgcn_s_setprio(1);
  do_mfma3<1>(af, bf, acc);
  __builtin_amdgcn_s_setprio(0);
  BAR();
  rd_a<2>(A0, wm, lr, kg, af);
  if (!LAST) {
    stage_64r(Bg, kb, t2, B0, tid);
    stage_64r(Bg + 64 * kb, kb, t2, B0 + 8192, tid);
  }
  BAR();
  __builtin_amdgcn_s_setprio(1);
  do_mfma3<2>(af, bf, acc);
  __builtin_amdgcn_s_setprio(0);
  BAR();
  rd_a<3>(A0, wm, lr, kg, af);
  if (!LAST) stage_64r(Bg + 128 * kb, kb, t2, B0 + 16384, tid);
  BAR();
  __builtin_amdgcn_s_setprio(1);
  do_mfma3<3>(af, bf, acc);
  __builtin_amdgcn_s_setprio(0);
  if (LAST)
    asm volatile("s_waitcnt vmcnt(0)" ::: "memory");
  else
    asm volatile("s_waitcnt vmcnt(3)" ::: "memory");
  BAR();
  rd_b3(B1, wn, lr, kg, bf);
  rd_a<0>(A1, wm, lr, kg, af);
  if (!LAST) {
    stage_64r(Ag, kb, t2, A0, tid);
    stage_64r(Ag + 64 * kb, kb, t2, A0 + 8192, tid);
  }
  BAR();
  __builtin_amdgcn_s_setprio(1);
  do_mfma3<0>(af, bf, acc);
  __builtin_amdgcn_s_setprio(0);
  BAR();
  rd_a<1>(A1, wm, lr, kg, af);
  if (!LAST) {
    stage_64r(Ag + 128 * kb, kb, t2, A0 + 16384, tid);
    stage_64r(Ag + 192 * kb, kb, t2, A0 + 24576, tid);
  }
  BAR();
  __builtin_amdgcn_s_setprio(1);
  do_mfma3<1>(af, bf, acc);
  __builtin_amdgcn_s_setprio(0);
  BAR();
  rd_a<2>(A1, wm, lr, kg, af);
  if (!LAST) {
    stage_64r(Bg, kb, t3, B1, tid);
    stage_64r(Bg + 64 * kb, kb, t3, B1 + 8192, tid);
  }
  BAR();
  __builtin_amdgcn_s_setprio(1);
  do_mfma3<2>(af, bf, acc);
  __builtin_amdgcn_s_setprio(0);
  BAR();
  rd_a<3>(A1, wm, lr, kg, af);
  if (!LAST) stage_64r(Bg + 128 * kb, kb, t3, B1 + 16384, tid);
  BAR();
  __builtin_amdgcn_s_setprio(1);
  do_mfma3<3>(af, bf, acc);
  __builtin_amdgcn_s_setprio(0);
  if (!LAST) asm volatile("s_waitcnt vmcnt(3)" ::: "memory");
  BAR();
}

__global__ __launch_bounds__(512, 2) void qkv_gemm192_kernel(
    const _Float16* __restrict__ A, const _Float16* __restrict__ Bt,
    const float* __restrict__ bias, _Float16* __restrict__ C) {
  extern __shared__ char smem[];
  const int NN = 3072;
  const size_t kb = 2048;
  const int tid = threadIdx.x;
  const int lane = tid & 63, wid = tid >> 6;
  const int lr = lane & 15, kg = lane >> 4;
  const int wm = (wid >> 2) * 128, wn = (wid & 3) * 48;
  const int bid = blockIdx.x;
  const int flat = (bid & 7) * 32 + (bid >> 3);
  const int bx = flat >> 4, by = flat & 15;
  const int m0 = bx * 256, n0 = by * 192;
  const char* Ag = (const char*)A + (size_t)m0 * kb;
  const char* Bg = (const char*)Bt + (size_t)n0 * kb;
  char* A0 = smem;
  char* B0 = smem + 65536;
  char* B1 = smem + 65536 + 24576;
  f32x4 acc[8][3] = {};
#pragma unroll
  for (int u = 0; u < 4; ++u)
    stage_64r(Ag + (size_t)(64 * u) * kb, kb, 0, A0 + u * 8192, tid);
#pragma unroll
  for (int u = 0; u < 3; ++u)
    stage_64r(Bg + (size_t)(64 * u) * kb, kb, 0, B0 + u * 8192, tid);
#pragma unroll
  for (int u = 0; u < 3; ++u)
    stage_64r(Bg + (size_t)(64 * u) * kb, kb, 1, B1 + u * 8192, tid);
  asm volatile("s_waitcnt vmcnt(3)" ::: "memory");
  BAR();
#pragma unroll 1
  for (int i = 0; i < 7; ++i)
    ktile_pair192<false>(Ag, Bg, kb, smem, tid, wm, wn, lr, kg, 2 * i + 1,
                         2 * i + 2, 2 * i + 3, acc);
  ktile_pair192<true>(Ag, Bg, kb, smem, tid, wm, wn, lr, kg, 15, 16, 17, acc);
#pragma unroll
  for (int nt = 0; nt < 3; ++nt) {
    const int col = n0 + wn + nt * 16 + lr;
    const float bv = bias[col];
#pragma unroll
    for (int mt = 0; mt < 8; ++mt) {
      const int row0 = m0 + wm + mt * 16 + kg * 4;
#pragma unroll
      for (int rr = 0; rr < 4; ++rr)
        C[(size_t)(row0 + rr) * NN + col] = (_Float16)(acc[mt][nt][rr] + bv);
    }
  }
}

// ================= 128x128 triple-buffered OUT GEMM (grid 256 = 32x8) =================
__global__ __launch_bounds__(512, 2) void out_gemm128_kernel(
    const _Float16* __restrict__ A, const _Float16* __restrict__ Bt,
    const float* __restrict__ bias, float* __restrict__ C) {
  extern __shared__ char smem[];
  const size_t kb = 2048;
  const int tid = threadIdx.x;
  const int lane = tid & 63, wid = tid >> 6;
  const int lr = lane & 15, kg = lane >> 4;
  const int wm = (wid >> 2) * 64, wn = (wid & 3) * 32;
  const int bid = blockIdx.x;
  const int flat = (bid & 7) * 32 + (bid >> 3);
  const int bx = flat >> 3, by = flat & 7;
  const int m0 = bx * 128, n0 = by * 128;
  const char* Ag = (const char*)A + (size_t)m0 * kb;
  const char* Bg = (const char*)Bt + (size_t)n0 * kb;
  f32x4 acc[4][2] = {};
  stage_half(Ag, kb, 0, smem, tid);
  stage_half(Bg, kb, 0, smem + 49152, tid);
  stage_half(Ag, kb, 1, smem + 16384, tid);
  stage_half(Bg, kb, 1, smem + 49152 + 16384, tid);
  asm volatile("s_waitcnt vmcnt(4)" ::: "memory");
  BAR();
#pragma unroll
  for (int t = 0; t < 16; ++t) {
    const char* At = smem + (t % 3) * 16384;
    const char* Bb = smem + 49152 + (t % 3) * 16384;
    f16x8 bf[2][2], af[4][2];
#pragma unroll
    for (int nt = 0; nt < 2; ++nt) {
      bf[nt][0] = ldsfrag(Bb, wn + nt * 16 + lr, kg);
      bf[nt][1] = ldsfrag(Bb, wn + nt * 16 + lr, 4 + kg);
    }
#pragma unroll
    for (int m = 0; m < 4; ++m) {
      af[m][0] = ldsfrag(At, wm + m * 16 + lr, kg);
      af[m][1] = ldsfrag(At, wm + m * 16 + lr, 4 + kg);
    }
    if (t < 14) {
      stage_half(Ag, kb, t + 2, smem + ((t + 2) % 3) * 16384, tid);
      stage_half(Bg, kb, t + 2, smem + 49152 + ((t + 2) % 3) * 16384, tid);
    }
    BAR();
    __builtin_amdgcn_s_setprio(1);
#pragma unroll
    for (int m = 0; m < 4; ++m)
#pragma unroll
      for (int nt = 0; nt < 2; ++nt) {
        acc[m][nt] = mfma16(af[m][0], bf[nt][0], acc[m][nt]);
        acc[m][nt] = mfma16(af[m][1], bf[nt][1], acc[m][nt]);
      }
    __builtin_amdgcn_s_setprio(0);
    if (t < 14)
      asm volatile("s_waitcnt vmcnt(4)" ::: "memory");
    else if (t == 14)
      asm volatile("s_waitcnt vmcnt(0)" ::: "memory");
    BAR();
  }
#pragma unroll
  for (int nt = 0; nt < 2; ++nt) {
    const int col = n0 + wn + nt * 16 + lr;
    const float bv = bias[col];
#pragma unroll
    for (int mt = 0; mt < 4; ++mt) {
      const int row0 = m0 + wm + mt * 16 + kg * 4;
#pragma unroll
      for (int rr = 0; rr < 4; ++rr)
        C[(size_t)(row0 + rr) * 1024 + col] = acc[mt][nt][rr] + bv;
    }
  }
}

// ---------------- fused windowed attention (K,Q,V all from qkvh) ----------------
__global__ __launch_bounds__(256) void attn_kernel(
    const _Float16* __restrict__ qkvh, const unsigned* __restrict__ masks,
    const int* __restrict__ sorted_idx, _Float16* __restrict__ attn_h) {
  __shared__ __align__(128) char sK[32768];  // K window [256][64] f16; later P
  __shared__ __align__(128) char sV[32768];  // V^T window [64][256] f16 (swizzled)
  const int flat = (blockIdx.x & 7) * 128 + (blockIdx.x >> 3);
  const int b = flat & 63, h = flat >> 6;
  const int tid = threadIdx.x, lane = tid & 63, wid = tid >> 6;
  const int W0 = min(max(64 * b - 96, 0), NSEQ - 256);
  const int lrow16 = lane & 15, kgrp = lane >> 4;
  int ridx[8];
#pragma unroll
  for (int c = 0; c < 8; ++c)
    ridx[c] = sorted_idx[W0 + c * 32 + wid * 8 + (lane >> 3)];
  // K staging via global_load_lds (swizzled source, linear dest)
#pragma unroll
  for (int c = 0; c < 8; ++c) {
    const int o = c * 4096 + wid * 1024 + lane * 16;
    const int row = o >> 7;
    const int inrow = (o & 127) ^ ((row & 7) << 4);
    glds16((const char*)qkvh + (size_t)ridx[c] * 6144 + 2048 + h * 128 + inrow,
           sK + o);
  }
  // V reg-stage: same gather pattern, raw rows into regs
  f16x8 vreg[8];
#pragma unroll
  for (int c = 0; c < 8; ++c) {
    const int o = c * 4096 + wid * 1024 + lane * 16;
    vreg[c] = *(const f16x8*)((const char*)qkvh + (size_t)ridx[c] * 6144 +
                              4096 + h * 128 + (o & 127));
  }
  const int p_base = b * 64 + wid * 16;
  const int orig_q = sorted_idx[p_base + lrow16];
  const char* qp = (const char*)qkvh + (size_t)orig_q * 6144 + h * 128 + kgrp * 16;
  const f16x8 aq0 = *(const f16x8*)qp;
  const f16x8 aq1 = *(const f16x8*)(qp + 64);
  // mask bits: 8 words per query row, 2 x uint4 loads
  unsigned mb[4];
#pragma unroll
  for (int r = 0; r < 4; ++r) {
    const int p = p_base + kgrp * 4 + r;
    const uint4 wa = *(const uint4*)&masks[p * 8];
    const uint4 wb = *(const uint4*)&masks[p * 8 + 4];
    const unsigned wsv[8] = {wa.x, wa.y, wa.z, wa.w, wb.x, wb.y, wb.z, wb.w};
    unsigned bits = 0;
#pragma unroll
    for (int n = 0; n < 16; ++n)
      bits |= ((wsv[n >> 1] >> (((n & 1) << 4) + lrow16)) & 1u) << n;
    mb[r] = bits;
  }
  // transpose-write V into sV (same swizzle as PV read): elem (k,d) at
  // d*512 + (2k ^ ((d&7)<<4))
#pragma unroll
  for (int c = 0; c < 8; ++c) {
    const int o = c * 4096 + wid * 1024 + lane * 16;
    const int k = o >> 7;
    const int d0 = (o & 127) >> 1;
#pragma unroll
    for (int e = 0; e < 8; ++e) {
      const int d = d0 + e;
      *(_Float16*)(sV + d * 512 + ((2 * k) ^ ((d & 7) << 4))) = vreg[c][e];
    }
  }
  __syncthreads();
  float sv[16][4];
#pragma unroll
  for (int n = 0; n < 16; ++n) {
    const int j = n * 16 + lrow16;
    const int sw = (j & 7) << 4;
    const char* kr = sK + j * 128;
    const f16x8 b0 = *(const f16x8*)(kr + ((kgrp * 16) ^ sw));
    const f16x8 b1 = *(const f16x8*)(kr + ((64 + kgrp * 16) ^ sw));
    f32x4 a = {};
    a = mfma16(aq0, b0, a);
    a = mfma16(aq1, b1, a);
#pragma unroll
    for (int r = 0; r < 4; ++r)
      sv[n][r] = ((mb[r] >> n) & 1u) ? a[r] * 0.125f : -1e30f;
  }
#pragma unroll
  for (int r = 0; r < 4; ++r) {
    float m = sv[0][r];
#pragma unroll
    for (int n = 1; n < 16; ++n) m = fmaxf(m, sv[n][r]);
    m = fmaxf(m, __shfl_xor(m, 1));
    m = fmaxf(m, __shfl_xor(m, 2));
    m = fmaxf(m, __shfl_xor(m, 4));
    m = fmaxf(m, __shfl_xor(m, 8));
    float s = 0.f;
#pragma unroll
    for (int n = 0; n < 16; ++n) {
      const float e = __expf(sv[n][r] - m);
      sv[n][r] = e;
      s += e;
    }
    s += __shfl_xor(s, 1);
    s += __shfl_xor(s, 2);
    s += __shfl_xor(s, 4);
    s += __shfl_xor(s, 8);
    const float rinv = 1.f / s;
#pragma unroll
    for (int n = 0; n < 16; ++n) sv[n][r] *= rinv;
  }
  __syncthreads();
#pragma unroll
  for (int n = 0; n < 16; ++n) {
#pragma unroll
    for (int r = 0; r < 4; ++r) {
      const int lr = wid * 16 + kgrp * 4 + r;
      const int cb = (n * 16 + lrow16) * 2;
      *(_Float16*)(sK + lr * 512 + (cb ^ ((lr & 7) << 4))) = (_Float16)sv[n][r];
    }
  }
  __syncthreads();
  f32x4 oacc[4] = {};
  const int arow = wid * 16 + lrow16;
  const int swa = (arow & 7) << 4;
#pragma unroll
  for (int kt = 0; kt < 8; ++kt) {
    const int kbo = kt * 64 + kgrp * 16;
    const f16x8 pa = *(const f16x8*)(sK + arow * 512 + (kbo ^ swa));
#pragma unroll
    for (int nt = 0; nt < 4; ++nt) {
      const int d = nt * 16 + lrow16;
      const f16x8 vb = *(const f16x8*)(sV + d * 512 + (kbo ^ ((d & 7) << 4)));
      oacc[nt] = mfma16(pa, vb, oacc[nt]);
    }
  }
#pragma unroll
  for (int r = 0; r < 4; ++r) {
    const int p = p_base + kgrp * 4 + r;
    const int orig = sorted_idx[p];
    _Float16* op = attn_h + (size_t)orig * DIMM + h * 64;
#pragma unroll
    for (int nt = 0; nt < 4; ++nt)
      op[nt * 16 + lrow16] = (_Float16)oacc[nt][r];
  }
}

// ---------------- launch ----------------
extern "C" void kernel_launch(void* const* d_in, const int* in_sizes, int n_in,
                              void* d_out, int out_size, void* d_ws, size_t ws_size,
                              hipStream_t stream) {
  const float* x = (const float*)d_in[0];
  const float* cc = (const float*)d_in[1];
  const float* Wqkv = (const float*)d_in[2];
  const float* bqkv = (const float*)d_in[3];
  const float* Wout = (const float*)d_in[4];
  const float* bout = (const float*)d_in[5];
  char* ws = (char*)d_ws;

  _Float16* xh = (_Float16*)(ws + 0);                 //  8 MB
  _Float16* wqkvt = (_Float16*)(ws + 8388608);        //  6 MB
  _Float16* woutt = (_Float16*)(ws + 14680064);       //  2 MB
  _Float16* qkvh = (_Float16*)(ws + 16777216);        // 24 MB
  _Float16* atnh = (_Float16*)(ws + 41943040);        //  8 MB
  int* sidx = (int*)(ws + 50331648);                  // 16 KB
  float* csort = (float*)(ws + 50348032);             // 16 KB
  unsigned* msk = (unsigned*)(ws + 50364416);         // 128 KB

  hipFuncSetAttribute((const void*)qkv_gemm192_kernel,
                      hipFuncAttributeMaxDynamicSharedMemorySize, 114688);
  hipFuncSetAttribute((const void*)out_gemm128_kernel,
                      hipFuncAttributeMaxDynamicSharedMemorySize, 98304);

  prep_kernel<<<3200, 256, 0, stream>>>(x, xh, Wqkv, wqkvt, Wout, woutt, cc,
                                        sidx, csort);
  mask_kernel<<<1024, 256, 0, stream>>>(csort, sidx, msk);
  qkv_gemm192_kernel<<<256, 512, 114688, stream>>>(xh, wqkvt, bqkv, qkvh);
  attn_kernel<<<1024, 256, 0, stream>>>(qkvh, msk, sidx, atnh);
  out_gemm128_kernel<<<256, 512, 98304, stream>>>(atnh, woutt, bout,
                                                  (float*)d_out);
}

// Round 7
// 101.418 us; speedup vs baseline: 1.8628x; 1.0808x over previous
//
#include <hip/hip_runtime.h>
#include <hip/hip_bf16.h>

typedef _Float16 f16x8 __attribute__((ext_vector_type(8)));
typedef float f32x4 __attribute__((ext_vector_type(4)));
typedef unsigned long long u64;

#define NSEQ 4096
#define DIMM 1024
#define NHEAD 16
#define HD 64
#define NQKV 3072

#define BAR() asm volatile("s_barrier" ::: "memory")

__device__ __forceinline__ f32x4 mfma16(f16x8 a, f16x8 b, f32x4 c) {
  return __builtin_amdgcn_mfma_f32_16x16x32_f16(a, b, c, 0, 0, 0);
}

__device__ __forceinline__ void glds16(const void* g, void* l) {
  __builtin_amdgcn_global_load_lds(
      (const __attribute__((address_space(1))) void*)g,
      (__attribute__((address_space(3))) void*)l, 16, 0, 0);
}

// ---------------- fused prep: convert_x + 2 transposes + rank_sort ----------------
__global__ __launch_bounds__(256) void prep_kernel(
    const float* __restrict__ x, _Float16* __restrict__ xh,
    const float* __restrict__ Wqkv, _Float16* __restrict__ wqkvt,
    const float* __restrict__ Wout, _Float16* __restrict__ woutt,
    const float* __restrict__ cc, int* __restrict__ sorted_idx,
    float* __restrict__ csort) {
  __shared__ __align__(16) char plds[16640];
  const int bid = blockIdx.x, t = threadIdx.x;
  if (bid < 2048) {
    const int i = bid * 256 + t;
    const float4 a = ((const float4*)x)[i * 2];
    const float4 b = ((const float4*)x)[i * 2 + 1];
    f16x8 o = {(_Float16)a.x, (_Float16)a.y, (_Float16)a.z, (_Float16)a.w,
               (_Float16)b.x, (_Float16)b.y, (_Float16)b.z, (_Float16)b.w};
    ((f16x8*)xh)[i] = o;
  } else if (bid < 3072) {
    const bool qkv = bid < 2816;
    const int sub = qkv ? bid - 2048 : bid - 2816;
    const float* W = qkv ? Wqkv : Wout;
    _Float16* Wt = qkv ? wqkvt : woutt;
    const int Nn = qkv ? 3072 : 1024;
    const int k0 = (sub & 15) * 64, n0 = (sub >> 4) * 64;
    float (*tile)[65] = (float(*)[65])plds;
    const int tx = t & 63, ty = t >> 6;
    for (int rr = ty; rr < 64; rr += 4)
      tile[rr][tx] = W[(size_t)(k0 + rr) * Nn + n0 + tx];
    __syncthreads();
    for (int ccn = ty; ccn < 64; ccn += 4)
      Wt[(size_t)(n0 + ccn) * 1024 + k0 + tx] = (_Float16)tile[tx][ccn];
  } else {
    float* sc = (float*)plds;
#pragma unroll
    for (int it = 0; it < 4; ++it) {
      const int i = it * 256 + t;
      ((float4*)sc)[i] = ((const float4*)cc)[i];
    }
    __syncthreads();
    const int elem = (bid - 3072) * 32 + (t >> 3);
    const int s = t & 7;
    const unsigned mybits = __float_as_uint(sc[elem]);
    int cnt = 0;
#pragma unroll 8
    for (int m = 0; m < 512; ++m) {
      const int j = s + (m << 3);
      const unsigned bj = __float_as_uint(sc[j]);
      cnt += (bj < mybits || (bj == mybits && j < elem)) ? 1 : 0;
    }
    cnt += __shfl_xor(cnt, 1);
    cnt += __shfl_xor(cnt, 2);
    cnt += __shfl_xor(cnt, 4);
    if (s == 0) {
      sorted_idx[cnt] = elem;
      csort[cnt] = sc[elem];
    }
  }
}

// ---------------- per-query exact top-64 within 192-window -> mask ----------------
// window W0 = clamp(64*(p/64) - 64, 0, NSEQ-192); top-64 of p provably inside.
// register bitonic over 256 slots (192 real + 64 pad=max), 1 query per wave.
__global__ __launch_bounds__(256) void mask_kernel(
    const float* __restrict__ csort, const int* __restrict__ sorted_idx,
    unsigned* __restrict__ masks) {
  __shared__ unsigned lm[4][8];
  const int tid = threadIdx.x, lane = tid & 63, wid = tid >> 6;
  const int p = blockIdx.x * 4 + wid;
  int W0 = 64 * (p >> 6) - 64;
  W0 = min(max(W0, 0), NSEQ - 192);
  const float cp = csort[p];
  u64 key[4];
#pragma unroll
  for (int r = 0; r < 3; ++r) {
    const int w = r * 64 + lane;
    const float d = fabsf(csort[W0 + w] - cp);
    key[r] = (((u64)__float_as_uint(d)) << 20) |
             (((u64)(unsigned)sorted_idx[W0 + w]) << 8) | (unsigned)w;
  }
  key[3] = ~0ull;
  if (lane < 8) lm[wid][lane] = 0u;
#pragma unroll
  for (int k = 2; k <= 256; k <<= 1) {
#pragma unroll
    for (int j = k >> 1; j > 0; j >>= 1) {
      if (j >= 64) {
        const int rj = j >> 6;
#pragma unroll
        for (int r = 0; r < 4; ++r) {
          const int rp = r ^ rj;
          if (rp > r) {
            const bool up = (((r * 64) & k) == 0);
            const u64 a = key[r], b2 = key[rp];
            const bool sw = (a > b2) == up;
            key[r] = sw ? b2 : a;
            key[rp] = sw ? a : b2;
          }
        }
      } else {
#pragma unroll
        for (int r = 0; r < 4; ++r) {
          const u64 pv = __shfl_xor(key[r], j);
          const bool up = (((r * 64 + lane) & k) == 0);
          const bool lower = ((lane & j) == 0);
          const bool takemin = (lower == up);
          const u64 mn = key[r] < pv ? key[r] : pv;
          const u64 mx = key[r] < pv ? pv : key[r];
          key[r] = takemin ? mn : mx;
        }
      }
    }
  }
  const unsigned w0 = (unsigned)(key[0] & 0xffu);
  atomicOr(&lm[wid][w0 >> 5], 1u << (w0 & 31u));
  __syncthreads();
  if (lane < 8) masks[p * 8 + lane] = lm[wid][lane];
}

// ================= shared GEMM helpers =================
__device__ __forceinline__ f16x8 ldsfrag(const char* base, int r, int g) {
  return *(const f16x8*)(base + r * 128 + ((g ^ (r & 7)) << 4));
}

__device__ __forceinline__ void stage_half(const char* gbase, size_t kb, int t,
                                           char* lds_half, int tid) {
#pragma unroll
  for (int s = 0; s < 2; ++s) {
    const int rel = tid * 16 + s * 8192;
    const int r = rel >> 7;
    const int g = (rel >> 4) & 7;
    const int gg = g ^ (r & 7);
    glds16(gbase + (size_t)r * kb + t * 128 + gg * 16, lds_half + rel);
  }
}

__device__ __forceinline__ void stage_64r(const char* gbase, size_t kb, int t,
                                          char* lds8k, int tid) {
  const int rel = tid * 16;
  const int r = rel >> 7;
  const int g = (rel >> 4) & 7;
  const int gg = g ^ (r & 7);
  glds16(gbase + (size_t)r * kb + t * 128 + gg * 16, lds8k + rel);
}

// ================= 256x192 8-phase QKV GEMM (grid 256 = 16x16) =================
__device__ __forceinline__ void rd_b3(const char* Bb, int wn, int lr, int kg,
                                      f16x8 (&bf)[3][2]) {
#pragma unroll
  for (int nt = 0; nt < 3; ++nt) {
    bf[nt][0] = ldsfrag(Bb, wn + nt * 16 + lr, kg);
    bf[nt][1] = ldsfrag(Bb, wn + nt * 16 + lr, 4 + kg);
  }
}

template <int Q>
__device__ __forceinline__ void rd_a(const char* Ab, int wm, int lr, int kg,
                                     f16x8 (&af)[2][2]) {
#pragma unroll
  for (int m = 0; m < 2; ++m) {
    af[m][0] = ldsfrag(Ab, wm + (2 * Q + m) * 16 + lr, kg);
    af[m][1] = ldsfrag(Ab, wm + (2 * Q + m) * 16 + lr, 4 + kg);
  }
}

template <int Q>
__device__ __forceinline__ void do_mfma3(const f16x8 (&af)[2][2],
                                         const f16x8 (&bf)[3][2],
                                         f32x4 (&acc)[8][3]) {
#pragma unroll
  for (int m = 0; m < 2; ++m)
#pragma unroll
    for (int nt = 0; nt < 3; ++nt) {
      acc[2 * Q + m][nt] = mfma16(af[m][0], bf[nt][0], acc[2 * Q + m][nt]);
      acc[2 * Q + m][nt] = mfma16(af[m][1], bf[nt][1], acc[2 * Q + m][nt]);
    }
}

template <bool LAST>
__device__ __forceinline__ void ktile_pair192(const char* Ag, const char* Bg,
                                              size_t kb, char* smem, int tid,
                                              int wm, int wn, int lr, int kg,
                                              int t1, int t2, int t3,
                                              f32x4 (&acc)[8][3]) {
  char* A0 = smem;
  char* A1 = smem + 32768;
  char* B0 = smem + 65536;
  char* B1 = smem + 65536 + 24576;
  f16x8 bf[3][2], af[2][2];
  rd_b3(B0, wn, lr, kg, bf);
  rd_a<0>(A0, wm, lr, kg, af);
  stage_64r(Ag, kb, t1, A1, tid);
  stage_64r(Ag + 64 * kb, kb, t1, A1 + 8192, tid);
  BAR();
  __builtin_amdgcn_s_setprio(1);
  do_mfma3<0>(af, bf, acc);
  __builtin_amdgcn_s_setprio(0);
  BAR();
  rd_a<1>(A0, wm, lr, kg, af);
  stage_64r(Ag + 128 * kb, kb, t1, A1 + 16384, tid);
  stage_64r(Ag + 192 * kb, kb, t1, A1 + 24576, tid);
  BAR();
  __builtin_amdgcn_s_setprio(1);
  do_mfma3<1>(af, bf, acc);
  __builtin_amdgcn_s_setprio(0);
  BAR();
  rd_a<2>(A0, wm, lr, kg, af);
  if (!LAST) {
    stage_64r(Bg, kb, t2, B0, tid);
    stage_64r(Bg + 64 * kb, kb, t2, B0 + 8192, tid);
  }
  BAR();
  __builtin_amdgcn_s_setprio(1);
  do_mfma3<2>(af, bf, acc);
  __builtin_amdgcn_s_setprio(0);
  BAR();
  rd_a<3>(A0, wm, lr, kg, af);
  if (!LAST) stage_64r(Bg + 128 * kb, kb, t2, B0 + 16384, tid);
  BAR();
  __builtin_amdgcn_s_setprio(1);
  do_mfma3<3>(af, bf, acc);
  __builtin_amdgcn_s_setprio(0);
  if (LAST)
    asm volatile("s_waitcnt vmcnt(0)" ::: "memory");
  else
    asm volatile("s_waitcnt vmcnt(3)" ::: "memory");
  BAR();
  rd_b3(B1, wn, lr, kg, bf);
  rd_a<0>(A1, wm, lr, kg, af);
  if (!LAST) {
    stage_64r(Ag, kb, t2, A0, tid);
    stage_64r(Ag + 64 * kb, kb, t2, A0 + 8192, tid);
  }
  BAR();
  __builtin_amdgcn_s_setprio(1);
  do_mfma3<0>(af, bf, acc);
  __builtin_amdgcn_s_setprio(0);
  BAR();
  rd_a<1>(A1, wm, lr, kg, af);
  if (!LAST) {
    stage_64r(Ag + 128 * kb, kb, t2, A0 + 16384, tid);
    stage_64r(Ag + 192 * kb, kb, t2, A0 + 24576, tid);
  }
  BAR();
  __builtin_amdgcn_s_setprio(1);
  do_mfma3<1>(af, bf, acc);
  __builtin_amdgcn_s_setprio(0);
  BAR();
  rd_a<2>(A1, wm, lr, kg, af);
  if (!LAST) {
    stage_64r(Bg, kb, t3, B1, tid);
    stage_64r(Bg + 64 * kb, kb, t3, B1 + 8192, tid);
  }
  BAR();
  __builtin_amdgcn_s_setprio(1);
  do_mfma3<2>(af, bf, acc);
  __builtin_amdgcn_s_setprio(0);
  BAR();
  rd_a<3>(A1, wm, lr, kg, af);
  if (!LAST) stage_64r(Bg + 128 * kb, kb, t3, B1 + 16384, tid);
  BAR();
  __builtin_amdgcn_s_setprio(1);
  do_mfma3<3>(af, bf, acc);
  __builtin_amdgcn_s_setprio(0);
  if (!LAST) asm volatile("s_waitcnt vmcnt(3)" ::: "memory");
  BAR();
}

__global__ __launch_bounds__(512, 2) void qkv_gemm192_kernel(
    const _Float16* __restrict__ A, const _Float16* __restrict__ Bt,
    const float* __restrict__ bias, _Float16* __restrict__ C) {
  extern __shared__ char smem[];
  const int NN = 3072;
  const size_t kb = 2048;
  const int tid = threadIdx.x;
  const int lane = tid & 63, wid = tid >> 6;
  const int lr = lane & 15, kg = lane >> 4;
  const int wm = (wid >> 2) * 128, wn = (wid & 3) * 48;
  const int bid = blockIdx.x;
  const int flat = (bid & 7) * 32 + (bid >> 3);
  const int bx = flat >> 4, by = flat & 15;
  const int m0 = bx * 256, n0 = by * 192;
  const char* Ag = (const char*)A + (size_t)m0 * kb;
  const char* Bg = (const char*)Bt + (size_t)n0 * kb;
  char* A0 = smem;
  char* B0 = smem + 65536;
  char* B1 = smem + 65536 + 24576;
  f32x4 acc[8][3] = {};
#pragma unroll
  for (int u = 0; u < 4; ++u)
    stage_64r(Ag + (size_t)(64 * u) * kb, kb, 0, A0 + u * 8192, tid);
#pragma unroll
  for (int u = 0; u < 3; ++u)
    stage_64r(Bg + (size_t)(64 * u) * kb, kb, 0, B0 + u * 8192, tid);
#pragma unroll
  for (int u = 0; u < 3; ++u)
    stage_64r(Bg + (size_t)(64 * u) * kb, kb, 1, B1 + u * 8192, tid);
  asm volatile("s_waitcnt vmcnt(3)" ::: "memory");
  BAR();
#pragma unroll 1
  for (int i = 0; i < 7; ++i)
    ktile_pair192<false>(Ag, Bg, kb, smem, tid, wm, wn, lr, kg, 2 * i + 1,
                         2 * i + 2, 2 * i + 3, acc);
  ktile_pair192<true>(Ag, Bg, kb, smem, tid, wm, wn, lr, kg, 15, 16, 17, acc);
#pragma unroll
  for (int nt = 0; nt < 3; ++nt) {
    const int col = n0 + wn + nt * 16 + lr;
    const float bv = bias[col];
#pragma unroll
    for (int mt = 0; mt < 8; ++mt) {
      const int row0 = m0 + wm + mt * 16 + kg * 4;
#pragma unroll
      for (int rr = 0; rr < 4; ++rr)
        C[(size_t)(row0 + rr) * NN + col] = (_Float16)(acc[mt][nt][rr] + bv);
    }
  }
}

// ================= 128x128 triple-buffered OUT GEMM (grid 256 = 32x8) =================
__global__ __launch_bounds__(512, 2) void out_gemm128_kernel(
    const _Float16* __restrict__ A, const _Float16* __restrict__ Bt,
    const float* __restrict__ bias, float* __restrict__ C) {
  extern __shared__ char smem[];
  const size_t kb = 2048;
  const int tid = threadIdx.x;
  const int lane = tid & 63, wid = tid >> 6;
  const int lr = lane & 15, kg = lane >> 4;
  const int wm = (wid >> 2) * 64, wn = (wid & 3) * 32;
  const int bid = blockIdx.x;
  const int flat = (bid & 7) * 32 + (bid >> 3);
  const int bx = flat >> 3, by = flat & 7;
  const int m0 = bx * 128, n0 = by * 128;
  const char* Ag = (const char*)A + (size_t)m0 * kb;
  const char* Bg = (const char*)Bt + (size_t)n0 * kb;
  f32x4 acc[4][2] = {};
  stage_half(Ag, kb, 0, smem, tid);
  stage_half(Bg, kb, 0, smem + 49152, tid);
  stage_half(Ag, kb, 1, smem + 16384, tid);
  stage_half(Bg, kb, 1, smem + 49152 + 16384, tid);
  asm volatile("s_waitcnt vmcnt(4)" ::: "memory");
  BAR();
#pragma unroll
  for (int t = 0; t < 16; ++t) {
    const char* At = smem + (t % 3) * 16384;
    const char* Bb = smem + 49152 + (t % 3) * 16384;
    f16x8 bf[2][2], af[4][2];
#pragma unroll
    for (int nt = 0; nt < 2; ++nt) {
      bf[nt][0] = ldsfrag(Bb, wn + nt * 16 + lr, kg);
      bf[nt][1] = ldsfrag(Bb, wn + nt * 16 + lr, 4 + kg);
    }
#pragma unroll
    for (int m = 0; m < 4; ++m) {
      af[m][0] = ldsfrag(At, wm + m * 16 + lr, kg);
      af[m][1] = ldsfrag(At, wm + m * 16 + lr, 4 + kg);
    }
    if (t < 14) {
      stage_half(Ag, kb, t + 2, smem + ((t + 2) % 3) * 16384, tid);
      stage_half(Bg, kb, t + 2, smem + 49152 + ((t + 2) % 3) * 16384, tid);
    }
    BAR();
    __builtin_amdgcn_s_setprio(1);
#pragma unroll
    for (int m = 0; m < 4; ++m)
#pragma unroll
      for (int nt = 0; nt < 2; ++nt) {
        acc[m][nt] = mfma16(af[m][0], bf[nt][0], acc[m][nt]);
        acc[m][nt] = mfma16(af[m][1], bf[nt][1], acc[m][nt]);
      }
    __builtin_amdgcn_s_setprio(0);
    if (t < 14)
      asm volatile("s_waitcnt vmcnt(4)" ::: "memory");
    else if (t == 14)
      asm volatile("s_waitcnt vmcnt(0)" ::: "memory");
    BAR();
  }
#pragma unroll
  for (int nt = 0; nt < 2; ++nt) {
    const int col = n0 + wn + nt * 16 + lr;
    const float bv = bias[col];
#pragma unroll
    for (int mt = 0; mt < 4; ++mt) {
      const int row0 = m0 + wm + mt * 16 + kg * 4;
#pragma unroll
      for (int rr = 0; rr < 4; ++rr)
        C[(size_t)(row0 + rr) * 1024 + col] = acc[mt][nt][rr] + bv;
    }
  }
}

// ---------------- fused windowed attention, 192-window ----------------
__global__ __launch_bounds__(256) void attn_kernel(
    const _Float16* __restrict__ qkvh, const unsigned* __restrict__ masks,
    const int* __restrict__ sorted_idx, _Float16* __restrict__ attn_h) {
  __shared__ __align__(128) char sK[24576];  // K [192][128B]; later P [64][384B]
  __shared__ __align__(128) char sV[24576];  // V^T [64][384B] (swizzled)
  const int flat = (blockIdx.x & 7) * 128 + (blockIdx.x >> 3);
  const int b = flat & 63, h = flat >> 6;
  const int tid = threadIdx.x, lane = tid & 63, wid = tid >> 6;
  const int W0 = min(max(64 * b - 64, 0), NSEQ - 192);
  const int lrow16 = lane & 15, kgrp = lane >> 4;
  int ridx[6];
#pragma unroll
  for (int c = 0; c < 6; ++c)
    ridx[c] = sorted_idx[W0 + c * 32 + wid * 8 + (lane >> 3)];
  // K staging via global_load_lds (swizzled source, linear dest)
#pragma unroll
  for (int c = 0; c < 6; ++c) {
    const int o = c * 4096 + wid * 1024 + lane * 16;
    const int row = o >> 7;
    const int inrow = (o & 127) ^ ((row & 7) << 4);
    glds16((const char*)qkvh + (size_t)ridx[c] * 6144 + 2048 + h * 128 + inrow,
           sK + o);
  }
  // V reg-stage
  f16x8 vreg[6];
#pragma unroll
  for (int c = 0; c < 6; ++c) {
    const int o = c * 4096 + wid * 1024 + lane * 16;
    vreg[c] = *(const f16x8*)((const char*)qkvh + (size_t)ridx[c] * 6144 +
                              4096 + h * 128 + (o & 127));
  }
  const int p_base = b * 64 + wid * 16;
  const int orig_q = sorted_idx[p_base + lrow16];
  const char* qp = (const char*)qkvh + (size_t)orig_q * 6144 + h * 128 + kgrp * 16;
  const f16x8 aq0 = *(const f16x8*)qp;
  const f16x8 aq1 = *(const f16x8*)(qp + 64);
  // mask bits: 6 words per query row (stride 8 words for alignment)
  unsigned mb[4];
#pragma unroll
  for (int r = 0; r < 4; ++r) {
    const int p = p_base + kgrp * 4 + r;
    const uint4 wa = *(const uint4*)&masks[p * 8];
    const uint2 wb2 = *(const uint2*)&masks[p * 8 + 4];
    const unsigned wsv[6] = {wa.x, wa.y, wa.z, wa.w, wb2.x, wb2.y};
    unsigned bits = 0;
#pragma unroll
    for (int n = 0; n < 12; ++n)
      bits |= ((wsv[n >> 1] >> (((n & 1) << 4) + lrow16)) & 1u) << n;
    mb[r] = bits;
  }
  // transpose-write V into sV, e-rotated so the 8 lanes of a k-row hit
  // 8 distinct banks: elem (k,d) at d*384 + (2k ^ ((d&7)<<4))
  const int lrot = lane & 7;
#pragma unroll
  for (int c = 0; c < 6; ++c) {
    const int o = c * 4096 + wid * 1024 + lane * 16;
    const int k = o >> 7;
    const int d0 = (o & 127) >> 1;
#pragma unroll
    for (int ee = 0; ee < 8; ++ee) {
      const int e = (ee + lrot) & 7;
      const int d = d0 + e;
      *(_Float16*)(sV + d * 384 + ((2 * k) ^ ((d & 7) << 4))) = vreg[c][e];
    }
  }
  __syncthreads();
  // S = Q K^T over 192 keys (12 n-tiles)
  float sv[12][4];
#pragma unroll
  for (int n = 0; n < 12; ++n) {
    const int j = n * 16 + lrow16;
    const int sw = (j & 7) << 4;
    const char* kr = sK + j * 128;
    const f16x8 b0 = *(const f16x8*)(kr + ((kgrp * 16) ^ sw));
    const f16x8 b1 = *(const f16x8*)(kr + ((64 + kgrp * 16) ^ sw));
    f32x4 a = {};
    a = mfma16(aq0, b0, a);
    a = mfma16(aq1, b1, a);
#pragma unroll
    for (int r = 0; r < 4; ++r)
      sv[n][r] = ((mb[r] >> n) & 1u) ? a[r] * 0.125f : -1e30f;
  }
#pragma unroll
  for (int r = 0; r < 4; ++r) {
    float m = sv[0][r];
#pragma unroll
    for (int n = 1; n < 12; ++n) m = fmaxf(m, sv[n][r]);
    m = fmaxf(m, __shfl_xor(m, 1));
    m = fmaxf(m, __shfl_xor(m, 2));
    m = fmaxf(m, __shfl_xor(m, 4));
    m = fmaxf(m, __shfl_xor(m, 8));
    float s = 0.f;
#pragma unroll
    for (int n = 0; n < 12; ++n) {
      const float e = __expf(sv[n][r] - m);
      sv[n][r] = e;
      s += e;
    }
    s += __shfl_xor(s, 1);
    s += __shfl_xor(s, 2);
    s += __shfl_xor(s, 4);
    s += __shfl_xor(s, 8);
    const float rinv = 1.f / s;
#pragma unroll
    for (int n = 0; n < 12; ++n) sv[n][r] *= rinv;
  }
  __syncthreads();
  // write P (fp16) into sK region: [64 qrows][192 keys], 384B rows, swizzled
#pragma unroll
  for (int n = 0; n < 12; ++n) {
#pragma unroll
    for (int r = 0; r < 4; ++r) {
      const int lr = wid * 16 + kgrp * 4 + r;
      const int cb = (n * 16 + lrow16) * 2;
      *(_Float16*)(sK + lr * 384 + (cb ^ ((lr & 7) << 4))) = (_Float16)sv[n][r];
    }
  }
  __syncthreads();
  // O = P V over 192 k-slots (6 kt)
  f32x4 oacc[4] = {};
  const int arow = wid * 16 + lrow16;
  const int swa = (arow & 7) << 4;
#pragma unroll
  for (int kt = 0; kt < 6; ++kt) {
    const int kbo = kt * 64 + kgrp * 16;
    const f16x8 pa = *(const f16x8*)(sK + arow * 384 + (kbo ^ swa));
#pragma unroll
    for (int nt = 0; nt < 4; ++nt) {
      const int d = nt * 16 + lrow16;
      const f16x8 vb = *(const f16x8*)(sV + d * 384 + (kbo ^ ((d & 7) << 4)));
      oacc[nt] = mfma16(pa, vb, oacc[nt]);
    }
  }
#pragma unroll
  for (int r = 0; r < 4; ++r) {
    const int p = p_base + kgrp * 4 + r;
    const int orig = sorted_idx[p];
    _Float16* op = attn_h + (size_t)orig * DIMM + h * 64;
#pragma unroll
    for (int nt = 0; nt < 4; ++nt)
      op[nt * 16 + lrow16] = (_Float16)oacc[nt][r];
  }
}

// ---------------- launch ----------------
extern "C" void kernel_launch(void* const* d_in, const int* in_sizes, int n_in,
                              void* d_out, int out_size, void* d_ws, size_t ws_size,
                              hipStream_t stream) {
  const float* x = (const float*)d_in[0];
  const float* cc = (const float*)d_in[1];
  const float* Wqkv = (const float*)d_in[2];
  const float* bqkv = (const float*)d_in[3];
  const float* Wout = (const float*)d_in[4];
  const float* bout = (const float*)d_in[5];
  char* ws = (char*)d_ws;

  _Float16* xh = (_Float16*)(ws + 0);                 //  8 MB
  _Float16* wqkvt = (_Float16*)(ws + 8388608);        //  6 MB
  _Float16* woutt = (_Float16*)(ws + 14680064);       //  2 MB
  _Float16* qkvh = (_Float16*)(ws + 16777216);        // 24 MB
  _Float16* atnh = (_Float16*)(ws + 41943040);        //  8 MB
  int* sidx = (int*)(ws + 50331648);                  // 16 KB
  float* csort = (float*)(ws + 50348032);             // 16 KB
  unsigned* msk = (unsigned*)(ws + 50364416);         // 128 KB

  hipFuncSetAttribute((const void*)qkv_gemm192_kernel,
                      hipFuncAttributeMaxDynamicSharedMemorySize, 114688);
  hipFuncSetAttribute((const void*)out_gemm128_kernel,
                      hipFuncAttributeMaxDynamicSharedMemorySize, 98304);

  prep_kernel<<<3200, 256, 0, stream>>>(x, xh, Wqkv, wqkvt, Wout, woutt, cc,
                                        sidx, csort);
  mask_kernel<<<1024, 256, 0, stream>>>(csort, sidx, msk);
  qkv_gemm192_kernel<<<256, 512, 114688, stream>>>(xh, wqkvt, bqkv, qkvh);
  attn_kernel<<<1024, 256, 0, stream>>>(qkvh, msk, sidx, atnh);
  out_gemm128_kernel<<<256, 512, 98304, stream>>>(atnh, woutt, bout,
                                                  (float*)d_out);
}